// Round 1
// 2157.184 us; speedup vs baseline: 1.1258x; 1.1258x over previous
//
#include <hip/hip_runtime.h>
#include <cstdint>
#include <cstddef>

// ---------------------------------------------------------------------------
// GraphUNetSmall, round 6: atomic-free CSR build via 2-level bucket sort.
//
// R5 post-mortem: hist8_k pinned at 22.8 G atomics/s == 780 GB/s / 32 B —
// every scattered device-scope atomicAdd is one 32B memory-side RMW; 8-deep
// pipelining changed nothing (throughput wall, not latency). Build was
// ~1.1-1.4 ms of 2.43 ms. Replace hist/reorder with:
//   bhist_k: per-16K-edge block LDS histogram over 1024-node buckets ->
//            (bucket-major, block-minor) count matrix. Stream-bound.
//   scan1/2/3 (in-place) over the count matrix: bucket record offsets.
//   bscat_k: LDS-rank scatter of packed records (dlow<<21|src, ea) into
//            bucket-contiguous regions (semi-coalesced ~134B runs).
//   bcsr_k:  one block per bucket; LDS 1024-bin hist + LDS scan -> exact
//            starts[] + CSR pool. Scatter confined to ~32-56KB L2 window.
// Per-set node ranges padded to 1024 so buckets never straddle sets; padded
// nodes get deg 0 so starts[d+1] stays correct in unchanged compute kernels.
// Stage II built in 2 ZoneD-sized groups. Total ws 203.3 MB (< proven 204.6).
// ---------------------------------------------------------------------------

#define DEV __device__ __forceinline__

static constexpr int NCc = 1000000;
static constexpr int NFc = 1500000;
static constexpr int N0c = 500000;
static constexpr int N1c = 125000;
static constexpr int N2c = 31250;
static constexpr int N3c = 7813;
static constexpr int N4c = 1954;
static constexpr int SCHUNK = 8192;   // elems per scan block (256 thr * 32)
static constexpr int CH = 16384;      // edges per bucket-build block (256*64)
static constexpr size_t ZDCAP = 17690000;  // ZoneD capacity, 4B units

// ---------------- bucketed CSR build (zero global atomics) ----------------

// Phase 1a: per-block LDS histogram over 1024-node buckets.
// histG layout per set: [bucket][block] (bucket-major) so the concatenated
// exclusive scan directly yields bucket-contiguous record offsets.
template<int NB>
__global__ void __launch_bounds__(256)
bhist_k(const int* __restrict__ dst, int* __restrict__ histG,
        int E, int nblk, int nbins)
{
    __shared__ int sh[NB];
    int j = blockIdx.x, t = threadIdx.x;
    for (int i = t; i < nbins; i += 256) sh[i] = 0;
    __syncthreads();
    int base = j * CH + t;
    for (int k0 = 0; k0 < 64; k0 += 8) {
        int d8[8];
#pragma unroll
        for (int k = 0; k < 8; ++k) {
            int e = base + (k0 + k) * 256;
            d8[k] = (e < E) ? dst[e] : -1;
        }
#pragma unroll
        for (int k = 0; k < 8; ++k)
            if (d8[k] >= 0) atomicAdd(&sh[d8[k] >> 10], 1);
    }
    __syncthreads();
    for (int i = t; i < nbins; i += 256) histG[i * nblk + j] = sh[i];
}

// Phase 1b: recompute local ranks with LDS atomics, scatter packed records
// (dlow<<21 | src, ea_bits) to bucket-contiguous positions. src < 2^21 ok
// (max src dim is NF = 1.5M).
template<int NB>
__global__ void __launch_bounds__(256)
bscat_k(const int* __restrict__ src, const int* __restrict__ dst,
        const float* __restrict__ ea, const int* __restrict__ scanS,
        int2* __restrict__ brec, int E, int nblk, int nbins)
{
    __shared__ int cnt[NB];
    __shared__ int bas[NB];
    int j = blockIdx.x, t = threadIdx.x;
    for (int i = t; i < nbins; i += 256) { cnt[i] = 0; bas[i] = scanS[i * nblk + j]; }
    __syncthreads();
    int base = j * CH + t;
    for (int k0 = 0; k0 < 64; k0 += 4) {
        int d4[4], s4[4]; float w4[4];
#pragma unroll
        for (int k = 0; k < 4; ++k) {
            int e = base + (k0 + k) * 256;
            d4[k] = (e < E) ? dst[e] : -1;
            s4[k] = (e < E) ? src[e] : 0;
            w4[k] = (e < E) ? ea[e] : 0.f;
        }
#pragma unroll
        for (int k = 0; k < 4; ++k) {
            if (d4[k] >= 0) {
                int bl = d4[k] >> 10;
                int r = atomicAdd(&cnt[bl], 1);
                brec[bas[bl] + r] =
                    make_int2(((d4[k] & 1023) << 21) | s4[k], __float_as_int(w4[k]));
            }
        }
    }
}

// Phase 2: one block per bucket (1024 nodes). Bucket records are contiguous
// at [scanS[b*nblk], scanS[(b+1)*nblk]) (next set's first entry / global
// sentinel terminates the last bucket). LDS hist + LDS scan -> starts + CSR.
__global__ void __launch_bounds__(256)
bcsr_k(const int2* __restrict__ brec, const int* __restrict__ scanS, int nblk,
       int* __restrict__ startsSet, int2* __restrict__ poolG, int sbias)
{
    __shared__ int cnt[1024];
    __shared__ int lst[1024];
    __shared__ int sd[256];
    int b = blockIdx.x, t = threadIdx.x;
    int bs = scanS[b * nblk];
    int be = scanS[(b + 1) * nblk];
    for (int i = t; i < 1024; i += 256) cnt[i] = 0;
    __syncthreads();
    // pass A: per-node counts
    int i = bs + t;
    for (; i + 768 < be; i += 1024) {
        int2 r0 = brec[i], r1 = brec[i + 256], r2 = brec[i + 512], r3 = brec[i + 768];
        atomicAdd(&cnt[(unsigned)r0.x >> 21], 1);
        atomicAdd(&cnt[(unsigned)r1.x >> 21], 1);
        atomicAdd(&cnt[(unsigned)r2.x >> 21], 1);
        atomicAdd(&cnt[(unsigned)r3.x >> 21], 1);
    }
    for (; i < be; i += 256) atomicAdd(&cnt[(unsigned)brec[i].x >> 21], 1);
    __syncthreads();
    // exclusive scan of cnt[1024] (4 per thread + block scan)
    int v0 = cnt[t * 4], v1 = cnt[t * 4 + 1], v2 = cnt[t * 4 + 2], v3 = cnt[t * 4 + 3];
    int s0 = v0 + v1 + v2 + v3;
    sd[t] = s0; __syncthreads();
    for (int off = 1; off < 256; off <<= 1) {
        int y = (t >= off) ? sd[t - off] : 0;
        __syncthreads();
        sd[t] += y;
        __syncthreads();
    }
    int run = sd[t] - s0;
    lst[t * 4]     = run; run += v0;
    lst[t * 4 + 1] = run; run += v1;
    lst[t * 4 + 2] = run; run += v2;
    lst[t * 4 + 3] = run;
    __syncthreads();
    // starts (padded nodes get correct boundary values)
    int gb = sbias + bs;
    for (int q = t; q < 1024; q += 256) startsSet[(b << 10) + q] = gb + lst[q];
    // pass B: scatter into final CSR pool (cursor = zeroed cnt)
    for (int q = t; q < 1024; q += 256) cnt[q] = 0;
    __syncthreads();
    i = bs + t;
    for (; i < be; i += 256) {
        int2 rec = brec[i];
        int dl = (unsigned)rec.x >> 21;
        int r = atomicAdd(&cnt[dl], 1);
        poolG[bs + lst[dl] + r] = make_int2(rec.x & 0x1FFFFF, rec.y);
    }
}

// ---------------- scans (scan1 now alias-safe for in-place use) ----------
__global__ void __launch_bounds__(256)
scan1_k(const int* deg, int* starts, int* part, int n)
{
    __shared__ int sd[256];
    int t = threadIdx.x;
    int base = blockIdx.x * SCHUNK + t * 32;
    int v[32]; int sum = 0;
#pragma unroll
    for (int k = 0; k < 32; ++k) { int i = base + k; v[k] = (i < n) ? deg[i] : 0; sum += v[k]; }
    sd[t] = sum; __syncthreads();
    for (int off = 1; off < 256; off <<= 1) {
        int y = (t >= off) ? sd[t - off] : 0;
        __syncthreads();
        sd[t] += y;
        __syncthreads();
    }
    int run = sd[t] - sum;                 // exclusive offset of this thread
#pragma unroll
    for (int k = 0; k < 32; ++k) { int i = base + k; if (i < n) starts[i] = run; run += v[k]; }
    if (t == 255) part[blockIdx.x] = sd[255];
}

__global__ void __launch_bounds__(1024)
scan2_k(int* __restrict__ part, int nb)   // exclusive scan of block sums, nb<=1024
{
    __shared__ int sd[1024];
    int t = threadIdx.x;
    int v = (t < nb) ? part[t] : 0;
    sd[t] = v; __syncthreads();
    for (int off = 1; off < 1024; off <<= 1) {
        int y = (t >= off) ? sd[t - off] : 0;
        __syncthreads();
        sd[t] += y;
        __syncthreads();
    }
    if (t < nb) part[t] = sd[t] - v;
}

__global__ void __launch_bounds__(256)
scan3_k(int* __restrict__ starts, const int* __restrict__ part, int n, int Etot)
{
    int i = blockIdx.x * 256 + threadIdx.x;
    if (i < n) starts[i] += part[i / SCHUNK];
    if (i == 0) starts[n] = Etot;          // sentinel terminates last bucket
}

// ---------------- compute (unchanged, proven) ----------------
template<int F>
DEV void row_fma(const float* __restrict__ p, float w, float* acc)
{
    if constexpr (F == 2) {
        float2 v = *reinterpret_cast<const float2*>(p);
        acc[0] = fmaf(w, v.x, acc[0]); acc[1] = fmaf(w, v.y, acc[1]);
    } else {
        static_assert(F % 4 == 0, "");
#pragma unroll
        for (int k = 0; k < F; k += 4) {
            float4 v = *reinterpret_cast<const float4*>(p + k);
            acc[k+0] = fmaf(w, v.x, acc[k+0]); acc[k+1] = fmaf(w, v.y, acc[k+1]);
            acc[k+2] = fmaf(w, v.z, acc[k+2]); acc[k+3] = fmaf(w, v.w, acc[k+3]);
        }
    }
}

template<int F, bool EPI>
__global__ void __launch_bounds__(256)
gather_sw_k(const float* __restrict__ x, const int2* __restrict__ ecsr,
            const int* __restrict__ starts, const float* __restrict__ b,
            float* __restrict__ out, int n)
{
    int d = blockIdx.x * 256 + threadIdx.x;
    if (d >= n) return;
    int i0 = starts[d], i1 = starts[d + 1];
    float acc[F];
#pragma unroll
    for (int k = 0; k < F; ++k) acc[k] = 0.f;
    for (int i = i0; i < i1; ++i) {
        int2 rec = ecsr[i];
        row_fma<F>(x + (size_t)rec.x * F, __int_as_float(rec.y), acc);
    }
    if constexpr (EPI) {
#pragma unroll
        for (int k = 0; k < F; ++k) acc[k] = fmaxf(acc[k] + b[k], 0.f);
    }
    float* op = out + (size_t)d * F;
#pragma unroll
    for (int k = 0; k < F; k += 4)
        *reinterpret_cast<float4*>(op + k) = make_float4(acc[k], acc[k+1], acc[k+2], acc[k+3]);
}

template<int FI1, int FI2, int FO>
__global__ void __launch_bounds__(256)
gather_conv_k(const float* __restrict__ x1, const float* __restrict__ x2,
              const int2* __restrict__ ecsr, const int* __restrict__ starts,
              const float* __restrict__ W, const float* __restrict__ b,
              float* __restrict__ out, int n)
{
    constexpr int FI = FI1 + FI2;
    __shared__ float sW[FI * FO];
    for (int i = threadIdx.x; i < FI * FO; i += 256) sW[i] = W[i];
    __syncthreads();
    int d = blockIdx.x * 256 + threadIdx.x;
    if (d >= n) return;
    int i0 = starts[d], i1 = starts[d + 1];
    float acc[FI];
#pragma unroll
    for (int k = 0; k < FI; ++k) acc[k] = 0.f;
    for (int i = i0; i < i1; ++i) {
        int2 rec = ecsr[i];
        float w = __int_as_float(rec.y);
        row_fma<FI1>(x1 + (size_t)rec.x * FI1, w, acc);
        if constexpr (FI2 > 0)
            row_fma<FI2>(x2 + (size_t)rec.x * FI2, w, acc + FI1);
    }
    float* op = out + (size_t)d * FO;
#pragma unroll
    for (int fo = 0; fo < FO; fo += 4) {
        float4 y; float* yp = &y.x;
#pragma unroll
        for (int j = 0; j < 4; ++j) {
            float s = b[fo + j];
#pragma unroll
            for (int k = 0; k < FI; ++k) s = fmaf(acc[k], sW[k * FO + fo + j], s);
            yp[j] = fmaxf(s, 0.f);
        }
        *reinterpret_cast<float4*>(op + fo) = y;
    }
}

template<int FI1, int FI2, int FO>
__global__ void __launch_bounds__(256)
dense2_k(const float* __restrict__ x1, const float* __restrict__ x2,
         const float* __restrict__ W, float* __restrict__ out, int n)
{
    constexpr int FI = FI1 + FI2;
    __shared__ float sW[FI * FO];
    for (int i = threadIdx.x; i < FI * FO; i += 256) sW[i] = W[i];
    __syncthreads();
    int d = blockIdx.x * 256 + threadIdx.x;
    if (d >= n) return;
    float xin[FI];
    {
        const float* p = x1 + (size_t)d * FI1;
#pragma unroll
        for (int k = 0; k < FI1; k += 4) {
            float4 v = *reinterpret_cast<const float4*>(p + k);
            xin[k] = v.x; xin[k+1] = v.y; xin[k+2] = v.z; xin[k+3] = v.w;
        }
    }
    if constexpr (FI2 > 0) {
        const float* p = x2 + (size_t)d * FI2;
#pragma unroll
        for (int k = 0; k < FI2; k += 4) {
            float4 v = *reinterpret_cast<const float4*>(p + k);
            xin[FI1+k] = v.x; xin[FI1+k+1] = v.y; xin[FI1+k+2] = v.z; xin[FI1+k+3] = v.w;
        }
    }
    float* op = out + (size_t)d * FO;
#pragma unroll
    for (int fo = 0; fo < FO; fo += 4) {
        float4 y; float* yp = &y.x;
#pragma unroll
        for (int j = 0; j < 4; ++j) {
            float s = 0.f;
#pragma unroll
            for (int k = 0; k < FI; ++k) s = fmaf(xin[k], sW[k * FO + fo + j], s);
            yp[j] = s;
        }
        *reinterpret_cast<float4*>(op + fo) = y;
    }
}

__global__ void __launch_bounds__(256)
gather_final_k(const float* __restrict__ x, const int2* __restrict__ ecsr,
               const int* __restrict__ starts, const float* __restrict__ b9b,
               const float* __restrict__ Wf, const float* __restrict__ bf,
               float* __restrict__ out, int n)
{
    int d = blockIdx.x * 256 + threadIdx.x;
    if (d >= n) return;
    int i0 = starts[d], i1 = starts[d + 1];
    float acc[16];
#pragma unroll
    for (int k = 0; k < 16; ++k) acc[k] = 0.f;
    for (int i = i0; i < i1; ++i) {
        int2 rec = ecsr[i];
        row_fma<16>(x + (size_t)rec.x * 16, __int_as_float(rec.y), acc);
    }
    float y = bf[0];
#pragma unroll
    for (int k = 0; k < 16; ++k) y = fmaf(fmaxf(acc[k] + b9b[k], 0.f), Wf[k], y);
    out[d] = y;
}

// ---------------- host ----------------
extern "C" void kernel_launch(void* const* d_in, const int* in_sizes, int n_in,
                              void* d_out, int out_size, void* d_ws, size_t ws_size,
                              hipStream_t stream)
{
    const float* xc = (const float*)d_in[0];
    const float* xf = (const float*)d_in[1];

    auto SRC = [&](int i) { return (const int*)d_in[i]; };
    auto DST = [&](int i) { return (const int*)d_in[i] + in_sizes[i] / 2; };
    auto EA  = [&](int i) { return (const float*)d_in[i + 1]; };
    auto EN  = [&](int i) { return in_sizes[i] / 2; };

    const float* W_cf=(const float*)d_in[34]; const float* b_cf=(const float*)d_in[35];
    const float* W_fp=(const float*)d_in[36]; const float* b_fp=(const float*)d_in[37];
    const float* W2  =(const float*)d_in[38]; const float* b2  =(const float*)d_in[39];
    const float* W3  =(const float*)d_in[40]; const float* b3  =(const float*)d_in[41];
    const float* W4  =(const float*)d_in[42]; const float* b4  =(const float*)d_in[43];
    const float* W5a =(const float*)d_in[44]; const float* b5a =(const float*)d_in[45];
    const float* W5b =(const float*)d_in[46]; const float* b5b =(const float*)d_in[47];
    const float* W6  =(const float*)d_in[48]; const float* b6  =(const float*)d_in[49];
    const float* W7  =(const float*)d_in[50]; const float* b7  =(const float*)d_in[51];
    const float* W8  =(const float*)d_in[52]; const float* b8  =(const float*)d_in[53];
    const float* W9a =(const float*)d_in[54]; const float* b9a =(const float*)d_in[55];
    const float* W9b =(const float*)d_in[56]; const float* b9b =(const float*)d_in[57];
    const float* Wf  =(const float*)d_in[58]; const float* bfb =(const float*)d_in[59];

    float* ws = (float*)d_ws;
    auto pad4 = [](size_t x) { return (x + 3) & ~(size_t)3; };
    auto nbinsOf = [](int nd) { return (nd + 1023) >> 10; };

    const int sI_in[2]  = {2, 4};
    const int sI_nd[2]  = {NFc, N0c};
    const int sII_in[14] = {6, 8, 10, 12, 14, 16, 18, 20, 22, 24, 26, 28, 30, 32};
    const int sII_nd[14] = {NCc, N0c, N1c, N2c, N3c, N4c, N1c, N2c, N3c, N4c,
                            N0c, N1c, N2c, N3c};

    // ---- zone sizing (4 B units). Node ranges padded to 1024 per set. ----
    size_t sumNdPadI = 0, sumEI = 0, sumNdPadII = 0, sumEII = 0;
    for (int t = 0; t < 2;  ++t) { sumNdPadI  += (size_t)nbinsOf(sI_nd[t])  << 10; sumEI  += EN(sI_in[t]); }
    for (int t = 0; t < 14; ++t) { sumNdPadII += (size_t)nbinsOf(sII_nd[t]) << 10; sumEII += EN(sII_in[t]); }
    size_t zI  = pad4(sumNdPadI  + 1) + pad4(2 * sumEI);
    size_t zII = pad4(sumNdPadII + 1) + pad4(2 * sumEII);
    size_t zAB = (zI > zII) ? zI : zII;                      // ~25.14M units
    size_t zC_o = zAB, zD_o = zAB + 8000000;
    size_t part_o = zD_o + ZDCAP;                            // +1024 ints
    // total ~50.83M units ~203.3 MB (< R4-proven 204.6 MB budget)

    int* part = (int*)(ws + part_o);
    const int B = 256;
    auto G = [&](int n) { return dim3((unsigned)((n + B - 1) / B)); };

    // Per-stage bucketed build. Groups sets so ZoneD holds 2*E records + the
    // (bucket,block) count matrix (+1 sentinel). No global memsets/atomics.
    auto buildStage = [&](int ns, const int* sin, const int* snd,
                          int* starts, int2* pool, int* doffOut) {
        int nbinsA[14], nblkA[14], eoffA[14];
        long long sumNdPad = 0, sumE = 0;
        for (int t = 0; t < ns; ++t) {
            int nd = snd[t], E = EN(sin[t]);
            doffOut[t] = (int)sumNdPad;
            nbinsA[t] = (nd + 1023) >> 10;
            sumNdPad += (long long)nbinsA[t] << 10;
            nblkA[t] = (E + CH - 1) / CH;
            eoffA[t] = (int)sumE;
            sumE += E;
        }
        int t0 = 0;
        while (t0 < ns) {
            long long cost = 0, gE = 0, LA = 0; int t1 = t0;
            while (t1 < ns) {
                long long c = 2LL * EN(sin[t1]) + (long long)nbinsA[t1] * nblkA[t1];
                if (t1 > t0 && cost + c + 1 > (long long)ZDCAP) break;
                cost += c; gE += EN(sin[t1]);
                LA += (long long)nbinsA[t1] * nblkA[t1];
                ++t1;
            }
            int2* brec = (int2*)(ws + zD_o);
            int*  hist = (int*)(ws + zD_o) + 2 * gE;
            long long hoff = 0;
            for (int t = t0; t < t1; ++t) {
                int E = EN(sin[t]);
                if (nbinsA[t] > 1024)
                    bhist_k<2048><<<dim3((unsigned)nblkA[t]), B, 0, stream>>>(
                        DST(sin[t]), hist + hoff, E, nblkA[t], nbinsA[t]);
                else
                    bhist_k<1024><<<dim3((unsigned)nblkA[t]), B, 0, stream>>>(
                        DST(sin[t]), hist + hoff, E, nblkA[t], nbinsA[t]);
                hoff += (long long)nbinsA[t] * nblkA[t];
            }
            int nb = (int)((LA + SCHUNK - 1) / SCHUNK);
            scan1_k<<<dim3((unsigned)nb), B, 0, stream>>>(hist, hist, part, (int)LA);
            scan2_k<<<dim3(1), 1024, 0, stream>>>(part, nb);
            scan3_k<<<G((int)LA + 1), B, 0, stream>>>(hist, part, (int)LA, (int)gE);
            hoff = 0;
            for (int t = t0; t < t1; ++t) {
                int E = EN(sin[t]);
                if (nbinsA[t] > 1024)
                    bscat_k<2048><<<dim3((unsigned)nblkA[t]), B, 0, stream>>>(
                        SRC(sin[t]), DST(sin[t]), EA(sin[t]),
                        hist + hoff, brec, E, nblkA[t], nbinsA[t]);
                else
                    bscat_k<1024><<<dim3((unsigned)nblkA[t]), B, 0, stream>>>(
                        SRC(sin[t]), DST(sin[t]), EA(sin[t]),
                        hist + hoff, brec, E, nblkA[t], nbinsA[t]);
                hoff += (long long)nbinsA[t] * nblkA[t];
            }
            int gBase = eoffA[t0];
            hoff = 0;
            for (int t = t0; t < t1; ++t) {
                bcsr_k<<<dim3((unsigned)nbinsA[t]), B, 0, stream>>>(
                    brec, hist + hoff, nblkA[t],
                    starts + doffOut[t], pool + gBase, gBase);
                hoff += (long long)nbinsA[t] * nblkA[t];
            }
            t0 = t1;
        }
    };

    // ---- feature buffers ----
    float* h   = ws + zD_o;                  // [NF,12], steps 1-2
    float* c1  = ws + zC_o;                  // [N0,16], steps 2-19
    float* tpc = c1;                         // steps 20-21 (c1 dead)
    size_t mb = zD_o;
    auto mal = [&](size_t n) { size_t o = mb; mb += pad4(n); return ws + o; };
    float* p1  = mal((size_t)N1c*16);
    float* c2  = mal((size_t)N1c*16);
    float* p2  = mal((size_t)N2c*16);
    float* c3  = mal((size_t)N2c*16);
    float* p3  = mal((size_t)N3c*16);
    float* c4  = mal((size_t)N3c*32);
    float* p4  = mal((size_t)N4c*32);
    float* c5a = mal((size_t)N4c*32);
    float* c5b = mal((size_t)N4c*32);
    float* u3  = mal((size_t)N3c*32);
    float* t6  = mal((size_t)N3c*32);
    float* g6  = mal((size_t)N3c*32);
    float* c6  = mal((size_t)N2c*32);
    float* t7  = mal((size_t)N2c*32);
    float* g7  = mal((size_t)N2c*32);
    float* c7  = mal((size_t)N1c*32);
    float* t8  = mal((size_t)N1c*16);
    float* g8  = mal((size_t)N1c*16);        // ends ~zD_o+17.31M <= ZDCAP
    float* c8  = ws + zD_o;                  // overlay [0,8M): mids dead by 18
    float* t9  = ws + zD_o + 8000000;        // overlay [8M,16M): dead by 19
    float* c9a = ws + zD_o;                  // overlay after c8 dies (19)
    float* out = (float*)d_out;

    // ---- Stage I: cf+fp CSRs (ZoneAB) + steps 1-2 ----
    int* startsI = (int*)(ws + 0);
    int2* poolI  = (int2*)(ws + pad4(sumNdPadI + 1));
    int doffI[2];
    buildStage(2, sI_in, sI_nd, startsI, poolI, doffI);
    // 1) h = relu(gather(cf, xc) @ W_cf + b_cf)                [NF,12]
    gather_conv_k<2,0,12><<<G(NFc), B, 0, stream>>>(
        xc, nullptr, poolI, startsI + doffI[0], W_cf, b_cf, h, NFc);
    // 2) c1 = relu(gather(fp, h||xf) @ W_fp + b_fp)            [N0,16]
    gather_conv_k<12,4,16><<<G(N0c), B, 0, stream>>>(
        h, xf, poolI, startsI + doffI[1], W_fp, b_fp, c1, N0c);

    // ---- Stage II: 14 remaining CSRs (ZoneAB rebuilt; temps over dead h) --
    int* startsII = (int*)(ws + 0);
    int2* poolII  = (int2*)(ws + pad4(sumNdPadII + 1));
    int doffII[14];
    buildStage(14, sII_in, sII_nd, startsII, poolII, doffII);
    enum { f_pc, f_pp0, f_pp1, f_pp2, f_pp3, f_pp4, f_po0, f_po1, f_po2, f_po3,
           f_up0, f_up1, f_up2, f_up3 };
    auto st = [&](int t) { return startsII + doffII[t]; };
    int2* ec = poolII;

    // ---- Stage III: pipeline (zero atomics) ----
    // 3) p1 = gather(pool0, c1)
    gather_sw_k<16,false><<<G(N1c), B, 0, stream>>>(c1, ec, st(f_po0), nullptr, p1, N1c);
    // 4) c2 = relu(gather(pp1, p1) @ W2 + b2)
    gather_conv_k<16,0,16><<<G(N1c), B, 0, stream>>>(p1, nullptr, ec, st(f_pp1), W2, b2, c2, N1c);
    // 5) p2
    gather_sw_k<16,false><<<G(N2c), B, 0, stream>>>(c2, ec, st(f_po1), nullptr, p2, N2c);
    // 6) c3
    gather_conv_k<16,0,16><<<G(N2c), B, 0, stream>>>(p2, nullptr, ec, st(f_pp2), W3, b3, c3, N2c);
    // 7) p3
    gather_sw_k<16,false><<<G(N3c), B, 0, stream>>>(c3, ec, st(f_po2), nullptr, p3, N3c);
    // 8) c4 = relu(gather(pp3, p3) @ W4 + b4)                  [N3,32]
    gather_conv_k<16,0,32><<<G(N3c), B, 0, stream>>>(p3, nullptr, ec, st(f_pp3), W4, b4, c4, N3c);
    // 9) p4
    gather_sw_k<32,false><<<G(N4c), B, 0, stream>>>(c4, ec, st(f_po3), nullptr, p4, N4c);
    // 10) c5a
    gather_conv_k<32,0,32><<<G(N4c), B, 0, stream>>>(p4, nullptr, ec, st(f_pp4), W5a, b5a, c5a, N4c);
    // 11) c5b
    gather_conv_k<32,0,32><<<G(N4c), B, 0, stream>>>(c5a, nullptr, ec, st(f_pp4), W5b, b5b, c5b, N4c);
    // 12) u3
    gather_sw_k<32,false><<<G(N3c), B, 0, stream>>>(c5b, ec, st(f_up3), nullptr, u3, N3c);
    // 13) g6: FI=64>FO=32 -> pre-transform then gather+bias+relu
    dense2_k<32,32,32><<<G(N3c), B, 0, stream>>>(u3, c4, W6, t6, N3c);
    gather_sw_k<32,true><<<G(N3c), B, 0, stream>>>(t6, ec, st(f_pp3), b6, g6, N3c);
    // 14) c6
    gather_sw_k<32,false><<<G(N2c), B, 0, stream>>>(g6, ec, st(f_up2), nullptr, c6, N2c);
    // 15) g7 (48->32 pre)
    dense2_k<32,16,32><<<G(N2c), B, 0, stream>>>(c6, c3, W7, t7, N2c);
    gather_sw_k<32,true><<<G(N2c), B, 0, stream>>>(t7, ec, st(f_pp2), b7, g7, N2c);
    // 16) c7
    gather_sw_k<32,false><<<G(N1c), B, 0, stream>>>(g7, ec, st(f_up1), nullptr, c7, N1c);
    // 17) g8 (48->16 pre)
    dense2_k<32,16,16><<<G(N1c), B, 0, stream>>>(c7, c2, W8, t8, N1c);
    gather_sw_k<16,true><<<G(N1c), B, 0, stream>>>(t8, ec, st(f_pp1), b8, g8, N1c);
    // 18) c8 = gather(unpool0, g8)   [N0,16] -> ZoneD[0,8M)
    gather_sw_k<16,false><<<G(N0c), B, 0, stream>>>(g8, ec, st(f_up0), nullptr, c8, N0c);
    // 19) c9a (32->16 pre): t9 in ZoneD[8M,16M), c9a overlays c8
    dense2_k<16,16,16><<<G(N0c), B, 0, stream>>>(c8, c1, W9a, t9, N0c);
    gather_sw_k<16,true><<<G(N0c), B, 0, stream>>>(t9, ec, st(f_pp0), b9a, c9a, N0c);
    // 20) pc conv pre-transform (N0 < NC); tpc overlays c1
    dense2_k<16,0,16><<<G(N0c), B, 0, stream>>>(c9a, nullptr, W9b, tpc, N0c);
    // 21) fused pc gather + bias + relu + Wf dot
    gather_final_k<<<G(NCc), B, 0, stream>>>(tpc, ec, st(f_pc), b9b, Wf, bfb, out, NCc);
}

// Round 2
// 2142.948 us; speedup vs baseline: 1.1332x; 1.0066x over previous
//
#include <hip/hip_runtime.h>
#include <cstdint>
#include <cstddef>

// ---------------------------------------------------------------------------
// GraphUNetSmall, round 7: kill the fp-conv over-fetch (R6's top dispatch).
//
// R6 post-mortem: gather_conv_k<12,4,16> (step 2) = 158us, FETCH 484MB at
// 42% HBM. Per edge it gathered a 48B h row (~1.75 lines, unaligned) + a
// separate 16B xf row (1 line) ~= 176B/edge for 64B of payload. Fix: gconv
// commutes -> pre-transform on the face side, fused into step 1:
//   cffp_k: per face, gather cf (xc rows 8B, L2/L3-resident), W_cf+b+relu
//           in regs, then t = [h12||xf] @ W_fp, ONE aligned 64B row store.
//           Also deletes the 72MB h write + 72MB random h re-read.
//   step2:  gather_sw_k<16,true> over fp: one 64B gather/edge + b_fp/relu.
// Layout: ZoneD -> zAB (build temps + mids), part after it, ZoneC (c1) at
// the tail (survives Stage-II build), t = [NF,16] (24M units) in scratch
// above the Stage-I CSR, dead after step 2. Total ~203MB (< proven budget).
// ---------------------------------------------------------------------------

#define DEV __device__ __forceinline__

static constexpr int NCc = 1000000;
static constexpr int NFc = 1500000;
static constexpr int N0c = 500000;
static constexpr int N1c = 125000;
static constexpr int N2c = 31250;
static constexpr int N3c = 7813;
static constexpr int N4c = 1954;
static constexpr int SCHUNK = 8192;   // elems per scan block (256 thr * 32)
static constexpr int CH = 16384;      // edges per bucket-build block (256*64)
static constexpr size_t ZDCAP = 17690000;  // ZoneD capacity, 4B units

// ---------------- bucketed CSR build (zero global atomics) ----------------

template<int NB>
__global__ void __launch_bounds__(256)
bhist_k(const int* __restrict__ dst, int* __restrict__ histG,
        int E, int nblk, int nbins)
{
    __shared__ int sh[NB];
    int j = blockIdx.x, t = threadIdx.x;
    for (int i = t; i < nbins; i += 256) sh[i] = 0;
    __syncthreads();
    int base = j * CH + t;
    for (int k0 = 0; k0 < 64; k0 += 8) {
        int d8[8];
#pragma unroll
        for (int k = 0; k < 8; ++k) {
            int e = base + (k0 + k) * 256;
            d8[k] = (e < E) ? dst[e] : -1;
        }
#pragma unroll
        for (int k = 0; k < 8; ++k)
            if (d8[k] >= 0) atomicAdd(&sh[d8[k] >> 10], 1);
    }
    __syncthreads();
    for (int i = t; i < nbins; i += 256) histG[i * nblk + j] = sh[i];
}

template<int NB>
__global__ void __launch_bounds__(256)
bscat_k(const int* __restrict__ src, const int* __restrict__ dst,
        const float* __restrict__ ea, const int* __restrict__ scanS,
        int2* __restrict__ brec, int E, int nblk, int nbins)
{
    __shared__ int cnt[NB];
    __shared__ int bas[NB];
    int j = blockIdx.x, t = threadIdx.x;
    for (int i = t; i < nbins; i += 256) { cnt[i] = 0; bas[i] = scanS[i * nblk + j]; }
    __syncthreads();
    int base = j * CH + t;
    for (int k0 = 0; k0 < 64; k0 += 4) {
        int d4[4], s4[4]; float w4[4];
#pragma unroll
        for (int k = 0; k < 4; ++k) {
            int e = base + (k0 + k) * 256;
            d4[k] = (e < E) ? dst[e] : -1;
            s4[k] = (e < E) ? src[e] : 0;
            w4[k] = (e < E) ? ea[e] : 0.f;
        }
#pragma unroll
        for (int k = 0; k < 4; ++k) {
            if (d4[k] >= 0) {
                int bl = d4[k] >> 10;
                int r = atomicAdd(&cnt[bl], 1);
                brec[bas[bl] + r] =
                    make_int2(((d4[k] & 1023) << 21) | s4[k], __float_as_int(w4[k]));
            }
        }
    }
}

__global__ void __launch_bounds__(256)
bcsr_k(const int2* __restrict__ brec, const int* __restrict__ scanS, int nblk,
       int* __restrict__ startsSet, int2* __restrict__ poolG, int sbias)
{
    __shared__ int cnt[1024];
    __shared__ int lst[1024];
    __shared__ int sd[256];
    int b = blockIdx.x, t = threadIdx.x;
    int bs = scanS[b * nblk];
    int be = scanS[(b + 1) * nblk];
    for (int i = t; i < 1024; i += 256) cnt[i] = 0;
    __syncthreads();
    int i = bs + t;
    for (; i + 768 < be; i += 1024) {
        int2 r0 = brec[i], r1 = brec[i + 256], r2 = brec[i + 512], r3 = brec[i + 768];
        atomicAdd(&cnt[(unsigned)r0.x >> 21], 1);
        atomicAdd(&cnt[(unsigned)r1.x >> 21], 1);
        atomicAdd(&cnt[(unsigned)r2.x >> 21], 1);
        atomicAdd(&cnt[(unsigned)r3.x >> 21], 1);
    }
    for (; i < be; i += 256) atomicAdd(&cnt[(unsigned)brec[i].x >> 21], 1);
    __syncthreads();
    int v0 = cnt[t * 4], v1 = cnt[t * 4 + 1], v2 = cnt[t * 4 + 2], v3 = cnt[t * 4 + 3];
    int s0 = v0 + v1 + v2 + v3;
    sd[t] = s0; __syncthreads();
    for (int off = 1; off < 256; off <<= 1) {
        int y = (t >= off) ? sd[t - off] : 0;
        __syncthreads();
        sd[t] += y;
        __syncthreads();
    }
    int run = sd[t] - s0;
    lst[t * 4]     = run; run += v0;
    lst[t * 4 + 1] = run; run += v1;
    lst[t * 4 + 2] = run; run += v2;
    lst[t * 4 + 3] = run;
    __syncthreads();
    int gb = sbias + bs;
    for (int q = t; q < 1024; q += 256) startsSet[(b << 10) + q] = gb + lst[q];
    for (int q = t; q < 1024; q += 256) cnt[q] = 0;
    __syncthreads();
    i = bs + t;
    for (; i < be; i += 256) {
        int2 rec = brec[i];
        int dl = (unsigned)rec.x >> 21;
        int r = atomicAdd(&cnt[dl], 1);
        poolG[bs + lst[dl] + r] = make_int2(rec.x & 0x1FFFFF, rec.y);
    }
}

// ---------------- scans (scan1 alias-safe for in-place use) ----------
__global__ void __launch_bounds__(256)
scan1_k(const int* deg, int* starts, int* part, int n)
{
    __shared__ int sd[256];
    int t = threadIdx.x;
    int base = blockIdx.x * SCHUNK + t * 32;
    int v[32]; int sum = 0;
#pragma unroll
    for (int k = 0; k < 32; ++k) { int i = base + k; v[k] = (i < n) ? deg[i] : 0; sum += v[k]; }
    sd[t] = sum; __syncthreads();
    for (int off = 1; off < 256; off <<= 1) {
        int y = (t >= off) ? sd[t - off] : 0;
        __syncthreads();
        sd[t] += y;
        __syncthreads();
    }
    int run = sd[t] - sum;
#pragma unroll
    for (int k = 0; k < 32; ++k) { int i = base + k; if (i < n) starts[i] = run; run += v[k]; }
    if (t == 255) part[blockIdx.x] = sd[255];
}

__global__ void __launch_bounds__(1024)
scan2_k(int* __restrict__ part, int nb)
{
    __shared__ int sd[1024];
    int t = threadIdx.x;
    int v = (t < nb) ? part[t] : 0;
    sd[t] = v; __syncthreads();
    for (int off = 1; off < 1024; off <<= 1) {
        int y = (t >= off) ? sd[t - off] : 0;
        __syncthreads();
        sd[t] += y;
        __syncthreads();
    }
    if (t < nb) part[t] = sd[t] - v;
}

__global__ void __launch_bounds__(256)
scan3_k(int* __restrict__ starts, const int* __restrict__ part, int n, int Etot)
{
    int i = blockIdx.x * 256 + threadIdx.x;
    if (i < n) starts[i] += part[i / SCHUNK];
    if (i == 0) starts[n] = Etot;
}

// ---------------- compute ----------------
template<int F>
DEV void row_fma(const float* __restrict__ p, float w, float* acc)
{
    if constexpr (F == 2) {
        float2 v = *reinterpret_cast<const float2*>(p);
        acc[0] = fmaf(w, v.x, acc[0]); acc[1] = fmaf(w, v.y, acc[1]);
    } else {
        static_assert(F % 4 == 0, "");
#pragma unroll
        for (int k = 0; k < F; k += 4) {
            float4 v = *reinterpret_cast<const float4*>(p + k);
            acc[k+0] = fmaf(w, v.x, acc[k+0]); acc[k+1] = fmaf(w, v.y, acc[k+1]);
            acc[k+2] = fmaf(w, v.z, acc[k+2]); acc[k+3] = fmaf(w, v.w, acc[k+3]);
        }
    }
}

// Fused step 1+1.5: per face, gather cf (xc 8B rows), W_cf+b_cf+relu in regs,
// then t = [h12||xf] @ W_fp -> one aligned 64B row. (b_fp/relu applied after
// the fp segment-sum in gather_sw_k's epilogue; gconv commutes with the
// per-src linear map.)
__global__ void __launch_bounds__(256)
cffp_k(const float* __restrict__ xc, const float* __restrict__ xf,
       const int2* __restrict__ ecsr, const int* __restrict__ starts,
       const float* __restrict__ W_cf, const float* __restrict__ b_cf,
       const float* __restrict__ W_fp, float* __restrict__ t, int n)
{
    __shared__ float sWcf[24];
    __shared__ float sbcf[12];
    __shared__ float sWfp[256];
    for (int i = threadIdx.x; i < 24;  i += 256) sWcf[i] = W_cf[i];
    for (int i = threadIdx.x; i < 12;  i += 256) sbcf[i] = b_cf[i];
    for (int i = threadIdx.x; i < 256; i += 256) sWfp[i] = W_fp[i];
    __syncthreads();
    int d = blockIdx.x * 256 + threadIdx.x;
    if (d >= n) return;
    int i0 = starts[d], i1 = starts[d + 1];
    float a0 = 0.f, a1 = 0.f;
    for (int i = i0; i < i1; ++i) {
        int2 rec = ecsr[i];
        float2 v = *reinterpret_cast<const float2*>(xc + (size_t)rec.x * 2);
        float w = __int_as_float(rec.y);
        a0 = fmaf(w, v.x, a0); a1 = fmaf(w, v.y, a1);
    }
    float h12[12];
#pragma unroll
    for (int j = 0; j < 12; ++j)
        h12[j] = fmaxf(fmaf(a0, sWcf[j], fmaf(a1, sWcf[12 + j], sbcf[j])), 0.f);
    float4 xfv = *reinterpret_cast<const float4*>(xf + (size_t)d * 4);
    float* op = t + (size_t)d * 16;
#pragma unroll
    for (int o = 0; o < 16; o += 4) {
        float4 y; float* yp = &y.x;
#pragma unroll
        for (int jj = 0; jj < 4; ++jj) {
            int oo = o + jj;
            float s =      xfv.x * sWfp[12 * 16 + oo];
            s = fmaf(xfv.y, sWfp[13 * 16 + oo], s);
            s = fmaf(xfv.z, sWfp[14 * 16 + oo], s);
            s = fmaf(xfv.w, sWfp[15 * 16 + oo], s);
#pragma unroll
            for (int j = 0; j < 12; ++j) s = fmaf(h12[j], sWfp[j * 16 + oo], s);
            yp[jj] = s;
        }
        *reinterpret_cast<float4*>(op + o) = y;
    }
}

template<int F, bool EPI>
__global__ void __launch_bounds__(256)
gather_sw_k(const float* __restrict__ x, const int2* __restrict__ ecsr,
            const int* __restrict__ starts, const float* __restrict__ b,
            float* __restrict__ out, int n)
{
    int d = blockIdx.x * 256 + threadIdx.x;
    if (d >= n) return;
    int i0 = starts[d], i1 = starts[d + 1];
    float acc[F];
#pragma unroll
    for (int k = 0; k < F; ++k) acc[k] = 0.f;
    for (int i = i0; i < i1; ++i) {
        int2 rec = ecsr[i];
        row_fma<F>(x + (size_t)rec.x * F, __int_as_float(rec.y), acc);
    }
    if constexpr (EPI) {
#pragma unroll
        for (int k = 0; k < F; ++k) acc[k] = fmaxf(acc[k] + b[k], 0.f);
    }
    float* op = out + (size_t)d * F;
#pragma unroll
    for (int k = 0; k < F; k += 4)
        *reinterpret_cast<float4*>(op + k) = make_float4(acc[k], acc[k+1], acc[k+2], acc[k+3]);
}

template<int FI1, int FI2, int FO>
__global__ void __launch_bounds__(256)
gather_conv_k(const float* __restrict__ x1, const float* __restrict__ x2,
              const int2* __restrict__ ecsr, const int* __restrict__ starts,
              const float* __restrict__ W, const float* __restrict__ b,
              float* __restrict__ out, int n)
{
    constexpr int FI = FI1 + FI2;
    __shared__ float sW[FI * FO];
    for (int i = threadIdx.x; i < FI * FO; i += 256) sW[i] = W[i];
    __syncthreads();
    int d = blockIdx.x * 256 + threadIdx.x;
    if (d >= n) return;
    int i0 = starts[d], i1 = starts[d + 1];
    float acc[FI];
#pragma unroll
    for (int k = 0; k < FI; ++k) acc[k] = 0.f;
    for (int i = i0; i < i1; ++i) {
        int2 rec = ecsr[i];
        float w = __int_as_float(rec.y);
        row_fma<FI1>(x1 + (size_t)rec.x * FI1, w, acc);
        if constexpr (FI2 > 0)
            row_fma<FI2>(x2 + (size_t)rec.x * FI2, w, acc + FI1);
    }
    float* op = out + (size_t)d * FO;
#pragma unroll
    for (int fo = 0; fo < FO; fo += 4) {
        float4 y; float* yp = &y.x;
#pragma unroll
        for (int j = 0; j < 4; ++j) {
            float s = b[fo + j];
#pragma unroll
            for (int k = 0; k < FI; ++k) s = fmaf(acc[k], sW[k * FO + fo + j], s);
            yp[j] = fmaxf(s, 0.f);
        }
        *reinterpret_cast<float4*>(op + fo) = y;
    }
}

template<int FI1, int FI2, int FO>
__global__ void __launch_bounds__(256)
dense2_k(const float* __restrict__ x1, const float* __restrict__ x2,
         const float* __restrict__ W, float* __restrict__ out, int n)
{
    constexpr int FI = FI1 + FI2;
    __shared__ float sW[FI * FO];
    for (int i = threadIdx.x; i < FI * FO; i += 256) sW[i] = W[i];
    __syncthreads();
    int d = blockIdx.x * 256 + threadIdx.x;
    if (d >= n) return;
    float xin[FI];
    {
        const float* p = x1 + (size_t)d * FI1;
#pragma unroll
        for (int k = 0; k < FI1; k += 4) {
            float4 v = *reinterpret_cast<const float4*>(p + k);
            xin[k] = v.x; xin[k+1] = v.y; xin[k+2] = v.z; xin[k+3] = v.w;
        }
    }
    if constexpr (FI2 > 0) {
        const float* p = x2 + (size_t)d * FI2;
#pragma unroll
        for (int k = 0; k < FI2; k += 4) {
            float4 v = *reinterpret_cast<const float4*>(p + k);
            xin[FI1+k] = v.x; xin[FI1+k+1] = v.y; xin[FI1+k+2] = v.z; xin[FI1+k+3] = v.w;
        }
    }
    float* op = out + (size_t)d * FO;
#pragma unroll
    for (int fo = 0; fo < FO; fo += 4) {
        float4 y; float* yp = &y.x;
#pragma unroll
        for (int j = 0; j < 4; ++j) {
            float s = 0.f;
#pragma unroll
            for (int k = 0; k < FI; ++k) s = fmaf(xin[k], sW[k * FO + fo + j], s);
            yp[j] = s;
        }
        *reinterpret_cast<float4*>(op + fo) = y;
    }
}

__global__ void __launch_bounds__(256)
gather_final_k(const float* __restrict__ x, const int2* __restrict__ ecsr,
               const int* __restrict__ starts, const float* __restrict__ b9b,
               const float* __restrict__ Wf, const float* __restrict__ bf,
               float* __restrict__ out, int n)
{
    int d = blockIdx.x * 256 + threadIdx.x;
    if (d >= n) return;
    int i0 = starts[d], i1 = starts[d + 1];
    float acc[16];
#pragma unroll
    for (int k = 0; k < 16; ++k) acc[k] = 0.f;
    for (int i = i0; i < i1; ++i) {
        int2 rec = ecsr[i];
        row_fma<16>(x + (size_t)rec.x * 16, __int_as_float(rec.y), acc);
    }
    float y = bf[0];
#pragma unroll
    for (int k = 0; k < 16; ++k) y = fmaf(fmaxf(acc[k] + b9b[k], 0.f), Wf[k], y);
    out[d] = y;
}

// ---------------- host ----------------
extern "C" void kernel_launch(void* const* d_in, const int* in_sizes, int n_in,
                              void* d_out, int out_size, void* d_ws, size_t ws_size,
                              hipStream_t stream)
{
    const float* xc = (const float*)d_in[0];
    const float* xf = (const float*)d_in[1];

    auto SRC = [&](int i) { return (const int*)d_in[i]; };
    auto DST = [&](int i) { return (const int*)d_in[i] + in_sizes[i] / 2; };
    auto EA  = [&](int i) { return (const float*)d_in[i + 1]; };
    auto EN  = [&](int i) { return in_sizes[i] / 2; };

    const float* W_cf=(const float*)d_in[34]; const float* b_cf=(const float*)d_in[35];
    const float* W_fp=(const float*)d_in[36]; const float* b_fp=(const float*)d_in[37];
    const float* W2  =(const float*)d_in[38]; const float* b2  =(const float*)d_in[39];
    const float* W3  =(const float*)d_in[40]; const float* b3  =(const float*)d_in[41];
    const float* W4  =(const float*)d_in[42]; const float* b4  =(const float*)d_in[43];
    const float* W5a =(const float*)d_in[44]; const float* b5a =(const float*)d_in[45];
    const float* W5b =(const float*)d_in[46]; const float* b5b =(const float*)d_in[47];
    const float* W6  =(const float*)d_in[48]; const float* b6  =(const float*)d_in[49];
    const float* W7  =(const float*)d_in[50]; const float* b7  =(const float*)d_in[51];
    const float* W8  =(const float*)d_in[52]; const float* b8  =(const float*)d_in[53];
    const float* W9a =(const float*)d_in[54]; const float* b9a =(const float*)d_in[55];
    const float* W9b =(const float*)d_in[56]; const float* b9b =(const float*)d_in[57];
    const float* Wf  =(const float*)d_in[58]; const float* bfb =(const float*)d_in[59];

    float* ws = (float*)d_ws;
    auto pad4 = [](size_t x) { return (x + 3) & ~(size_t)3; };
    auto nbinsOf = [](int nd) { return (nd + 1023) >> 10; };

    const int sI_in[2]  = {2, 4};
    const int sI_nd[2]  = {NFc, N0c};
    const int sII_in[14] = {6, 8, 10, 12, 14, 16, 18, 20, 22, 24, 26, 28, 30, 32};
    const int sII_nd[14] = {NCc, N0c, N1c, N2c, N3c, N4c, N1c, N2c, N3c, N4c,
                            N0c, N1c, N2c, N3c};

    // ---- zone sizing (4 B units); node ranges padded to 1024 per set ----
    size_t sumNdPadI = 0, sumEI = 0, sumNdPadII = 0, sumEII = 0;
    for (int t = 0; t < 2;  ++t) { sumNdPadI  += (size_t)nbinsOf(sI_nd[t])  << 10; sumEI  += EN(sI_in[t]); }
    for (int t = 0; t < 14; ++t) { sumNdPadII += (size_t)nbinsOf(sII_nd[t]) << 10; sumEII += EN(sII_in[t]); }
    size_t zI  = pad4(sumNdPadI  + 1) + pad4(2 * sumEI);
    size_t zII = pad4(sumNdPadII + 1) + pad4(2 * sumEII);
    size_t zAB = (zI > zII) ? zI : zII;                      // ~25.4M units
    // New layout: ZoneD (build temps + mids) right after ZoneAB; part after
    // ZoneD; ZoneC (c1) at the tail where nothing else ever writes.
    size_t zD_o   = zAB;
    size_t part_o = zD_o + ZDCAP;
    size_t zC_o   = part_o + 1024;
    // t (fp pre-transform, [NF,16]) lives above the Stage-I CSR, dead by
    // the end of step 2, before ZoneD's Stage-II build touches [zAB, ...).
    size_t t_o    = zI;                                       // 24M units
    // total = zC_o + 8M ~= 50.8M units ~203MB (< R4-proven 204.6MB)

    int* part = (int*)(ws + part_o);
    const int B = 256;
    auto G = [&](int n) { return dim3((unsigned)((n + B - 1) / B)); };

    auto buildStage = [&](int ns, const int* sin, const int* snd,
                          int* starts, int2* pool, int* doffOut) {
        int nbinsA[14], nblkA[14], eoffA[14];
        long long sumNdPad = 0, sumE = 0;
        for (int t = 0; t < ns; ++t) {
            int nd = snd[t], E = EN(sin[t]);
            doffOut[t] = (int)sumNdPad;
            nbinsA[t] = (nd + 1023) >> 10;
            sumNdPad += (long long)nbinsA[t] << 10;
            nblkA[t] = (E + CH - 1) / CH;
            eoffA[t] = (int)sumE;
            sumE += E;
        }
        int t0 = 0;
        while (t0 < ns) {
            long long cost = 0, gE = 0, LA = 0; int t1 = t0;
            while (t1 < ns) {
                long long c = 2LL * EN(sin[t1]) + (long long)nbinsA[t1] * nblkA[t1];
                if (t1 > t0 && cost + c + 1 > (long long)ZDCAP) break;
                cost += c; gE += EN(sin[t1]);
                LA += (long long)nbinsA[t1] * nblkA[t1];
                ++t1;
            }
            int2* brec = (int2*)(ws + zD_o);
            int*  hist = (int*)(ws + zD_o) + 2 * gE;
            long long hoff = 0;
            for (int t = t0; t < t1; ++t) {
                int E = EN(sin[t]);
                if (nbinsA[t] > 1024)
                    bhist_k<2048><<<dim3((unsigned)nblkA[t]), B, 0, stream>>>(
                        DST(sin[t]), hist + hoff, E, nblkA[t], nbinsA[t]);
                else
                    bhist_k<1024><<<dim3((unsigned)nblkA[t]), B, 0, stream>>>(
                        DST(sin[t]), hist + hoff, E, nblkA[t], nbinsA[t]);
                hoff += (long long)nbinsA[t] * nblkA[t];
            }
            int nb = (int)((LA + SCHUNK - 1) / SCHUNK);
            scan1_k<<<dim3((unsigned)nb), B, 0, stream>>>(hist, hist, part, (int)LA);
            scan2_k<<<dim3(1), 1024, 0, stream>>>(part, nb);
            scan3_k<<<G((int)LA + 1), B, 0, stream>>>(hist, part, (int)LA, (int)gE);
            hoff = 0;
            for (int t = t0; t < t1; ++t) {
                int E = EN(sin[t]);
                if (nbinsA[t] > 1024)
                    bscat_k<2048><<<dim3((unsigned)nblkA[t]), B, 0, stream>>>(
                        SRC(sin[t]), DST(sin[t]), EA(sin[t]),
                        hist + hoff, brec, E, nblkA[t], nbinsA[t]);
                else
                    bscat_k<1024><<<dim3((unsigned)nblkA[t]), B, 0, stream>>>(
                        SRC(sin[t]), DST(sin[t]), EA(sin[t]),
                        hist + hoff, brec, E, nblkA[t], nbinsA[t]);
                hoff += (long long)nbinsA[t] * nblkA[t];
            }
            int gBase = eoffA[t0];
            hoff = 0;
            for (int t = t0; t < t1; ++t) {
                bcsr_k<<<dim3((unsigned)nbinsA[t]), B, 0, stream>>>(
                    brec, hist + hoff, nblkA[t],
                    starts + doffOut[t], pool + gBase, gBase);
                hoff += (long long)nbinsA[t] * nblkA[t];
            }
            t0 = t1;
        }
    };

    // ---- feature buffers ----
    float* t   = ws + t_o;                   // [NF,16] fp pre-transform, 1-2
    float* c1  = ws + zC_o;                  // [N0,16], steps 2-19 (tail zone)
    float* tpc = c1;                         // steps 20-21 (c1 dead)
    size_t mb = zD_o;
    auto mal = [&](size_t n) { size_t o = mb; mb += pad4(n); return ws + o; };
    float* p1  = mal((size_t)N1c*16);
    float* c2  = mal((size_t)N1c*16);
    float* p2  = mal((size_t)N2c*16);
    float* c3  = mal((size_t)N2c*16);
    float* p3  = mal((size_t)N3c*16);
    float* c4  = mal((size_t)N3c*32);
    float* p4  = mal((size_t)N4c*32);
    float* c5a = mal((size_t)N4c*32);
    float* c5b = mal((size_t)N4c*32);
    float* u3  = mal((size_t)N3c*32);
    float* t6  = mal((size_t)N3c*32);
    float* g6  = mal((size_t)N3c*32);
    float* c6  = mal((size_t)N2c*32);
    float* t7  = mal((size_t)N2c*32);
    float* g7  = mal((size_t)N2c*32);
    float* c7  = mal((size_t)N1c*32);
    float* t8  = mal((size_t)N1c*16);
    float* g8  = mal((size_t)N1c*16);        // ends ~zD_o+17.31M <= ZDCAP
    float* c8  = ws + zD_o;                  // overlay [0,8M): mids dead by 18
    float* t9  = ws + zD_o + 8000000;        // overlay [8M,16M): dead by 19
    float* c9a = ws + zD_o;                  // overlay after c8 dies (19)
    float* out = (float*)d_out;

    // ---- Stage I: cf+fp CSRs (ZoneAB+ZoneD temps) + steps 1-2 ----
    int* startsI = (int*)(ws + 0);
    int2* poolI  = (int2*)(ws + pad4(sumNdPadI + 1));
    int doffI[2];
    buildStage(2, sI_in, sI_nd, startsI, poolI, doffI);
    // 1) fused: h = relu(gather(cf,xc)@W_cf+b_cf); t = [h||xf]@W_fp  [NF,16]
    cffp_k<<<G(NFc), B, 0, stream>>>(
        xc, xf, poolI, startsI + doffI[0], W_cf, b_cf, W_fp, t, NFc);
    // 2) c1 = relu(gather(fp, t) + b_fp)                       [N0,16]
    gather_sw_k<16,true><<<G(N0c), B, 0, stream>>>(
        t, poolI, startsI + doffI[1], b_fp, c1, N0c);

    // ---- Stage II: 14 remaining CSRs (t dead; ZoneAB+ZoneD rebuilt) ----
    int* startsII = (int*)(ws + 0);
    int2* poolII  = (int2*)(ws + pad4(sumNdPadII + 1));
    int doffII[14];
    buildStage(14, sII_in, sII_nd, startsII, poolII, doffII);
    enum { f_pc, f_pp0, f_pp1, f_pp2, f_pp3, f_pp4, f_po0, f_po1, f_po2, f_po3,
           f_up0, f_up1, f_up2, f_up3 };
    auto st = [&](int t_) { return startsII + doffII[t_]; };
    int2* ec = poolII;

    // ---- Stage III: pipeline (zero atomics) ----
    gather_sw_k<16,false><<<G(N1c), B, 0, stream>>>(c1, ec, st(f_po0), nullptr, p1, N1c);
    gather_conv_k<16,0,16><<<G(N1c), B, 0, stream>>>(p1, nullptr, ec, st(f_pp1), W2, b2, c2, N1c);
    gather_sw_k<16,false><<<G(N2c), B, 0, stream>>>(c2, ec, st(f_po1), nullptr, p2, N2c);
    gather_conv_k<16,0,16><<<G(N2c), B, 0, stream>>>(p2, nullptr, ec, st(f_pp2), W3, b3, c3, N2c);
    gather_sw_k<16,false><<<G(N3c), B, 0, stream>>>(c3, ec, st(f_po2), nullptr, p3, N3c);
    gather_conv_k<16,0,32><<<G(N3c), B, 0, stream>>>(p3, nullptr, ec, st(f_pp3), W4, b4, c4, N3c);
    gather_sw_k<32,false><<<G(N4c), B, 0, stream>>>(c4, ec, st(f_po3), nullptr, p4, N4c);
    gather_conv_k<32,0,32><<<G(N4c), B, 0, stream>>>(p4, nullptr, ec, st(f_pp4), W5a, b5a, c5a, N4c);
    gather_conv_k<32,0,32><<<G(N4c), B, 0, stream>>>(c5a, nullptr, ec, st(f_pp4), W5b, b5b, c5b, N4c);
    gather_sw_k<32,false><<<G(N3c), B, 0, stream>>>(c5b, ec, st(f_up3), nullptr, u3, N3c);
    dense2_k<32,32,32><<<G(N3c), B, 0, stream>>>(u3, c4, W6, t6, N3c);
    gather_sw_k<32,true><<<G(N3c), B, 0, stream>>>(t6, ec, st(f_pp3), b6, g6, N3c);
    gather_sw_k<32,false><<<G(N2c), B, 0, stream>>>(g6, ec, st(f_up2), nullptr, c6, N2c);
    dense2_k<32,16,32><<<G(N2c), B, 0, stream>>>(c6, c3, W7, t7, N2c);
    gather_sw_k<32,true><<<G(N2c), B, 0, stream>>>(t7, ec, st(f_pp2), b7, g7, N2c);
    gather_sw_k<32,false><<<G(N1c), B, 0, stream>>>(g7, ec, st(f_up1), nullptr, c7, N1c);
    dense2_k<32,16,16><<<G(N1c), B, 0, stream>>>(c7, c2, W8, t8, N1c);
    gather_sw_k<16,true><<<G(N1c), B, 0, stream>>>(t8, ec, st(f_pp1), b8, g8, N1c);
    gather_sw_k<16,false><<<G(N0c), B, 0, stream>>>(g8, ec, st(f_up0), nullptr, c8, N0c);
    dense2_k<16,16,16><<<G(N0c), B, 0, stream>>>(c8, c1, W9a, t9, N0c);
    gather_sw_k<16,true><<<G(N0c), B, 0, stream>>>(t9, ec, st(f_pp0), b9a, c9a, N0c);
    dense2_k<16,0,16><<<G(N0c), B, 0, stream>>>(c9a, nullptr, W9b, tpc, N0c);
    gather_final_k<<<G(NCc), B, 0, stream>>>(tpc, ec, st(f_pc), b9b, Wf, bfb, out, NCc);
}

// Round 5
// 1619.086 us; speedup vs baseline: 1.4999x; 1.3236x over previous
//
#include <hip/hip_runtime.h>
#include <cstdint>
#include <cstddef>

// ---------------------------------------------------------------------------
// GraphUNetSmall, round 10: resubmit of R9 (infra failure: "container failed
// twice", no test verdict). R9 = R8 multi-set build + gather/dense fusion
// with the t9 workspace-overflow fix:
//   - t9 overlays zD_o[0,8M) (mids there dead by step 18; g8 at
//     [10.06M,12.06M) and c1 in tail zone are disjoint). Arena 12.06M <=
//     ZDCAP=17.69M; total ws 203.3MB.
//   - mhist/mscat/mcsr: one launch per group via BuildTab (build 57->18).
//   - gather_dense_k: dense folded into gather epilogue (u3/c6/c7/c8/c9a
//     never materialize; -220MB traffic, -5 launches).
// Audited: build grouping (StageII g1 = pc..pp4, 17,675,360 <= ZDCAP incl
// sentinel), NB=2048 path for cf (nbins=1465), scan2 nb<=44, uniform
// barriers, kernarg < 4KB.
// ---------------------------------------------------------------------------

#define DEV __device__ __forceinline__

static constexpr int NCc = 1000000;
static constexpr int NFc = 1500000;
static constexpr int N0c = 500000;
static constexpr int N1c = 125000;
static constexpr int N2c = 31250;
static constexpr int N3c = 7813;
static constexpr int N4c = 1954;
static constexpr int SCHUNK = 8192;   // elems per scan block (256 thr * 32)
static constexpr int CH = 16384;      // edges per bucket-build block (256*64)
static constexpr size_t ZDCAP = 17690000;  // ZoneD capacity, 4B units

// Per-group set table for the fused build kernels (kernarg, <=4KB).
struct BuildTab {
    const int*   src[14];
    const int*   dst[14];
    const float* ea[14];
    int chunkBase[15];   // prefix of nblk
    int binBase[15];     // prefix of nbins
    int moff[14];        // matrix offset = prefix of nbins*nblk
    int doff[14];        // absolute starts-array offset of set
    int E[14];
    int nblk[14];
    int nbins[14];
    int nsets;
};

// ---------------- bucketed CSR build (zero global atomics) ----------------

template<int NB>
__global__ void __launch_bounds__(256)
mhist_k(BuildTab tab, int* __restrict__ histG)
{
    __shared__ int sh[NB];
    int j = blockIdx.x, t = 0;
    while (j >= tab.chunkBase[t + 1]) ++t;
    int lj = j - tab.chunkBase[t];
    int nbins = tab.nbins[t], nblk = tab.nblk[t], E = tab.E[t];
    const int* __restrict__ dst = tab.dst[t];
    int* hg = histG + tab.moff[t];
    int tx = threadIdx.x;
    for (int i = tx; i < nbins; i += 256) sh[i] = 0;
    __syncthreads();
    int base = lj * CH + tx;
    for (int k0 = 0; k0 < 64; k0 += 8) {
        int d8[8];
#pragma unroll
        for (int k = 0; k < 8; ++k) {
            int e = base + (k0 + k) * 256;
            d8[k] = (e < E) ? dst[e] : -1;
        }
#pragma unroll
        for (int k = 0; k < 8; ++k)
            if (d8[k] >= 0) atomicAdd(&sh[d8[k] >> 10], 1);
    }
    __syncthreads();
    for (int i = tx; i < nbins; i += 256) hg[i * nblk + lj] = sh[i];
}

template<int NB>
__global__ void __launch_bounds__(256)
mscat_k(BuildTab tab, const int* __restrict__ scanS, int2* __restrict__ brec)
{
    __shared__ int cnt[NB];
    __shared__ int bas[NB];
    int j = blockIdx.x, t = 0;
    while (j >= tab.chunkBase[t + 1]) ++t;
    int lj = j - tab.chunkBase[t];
    int nbins = tab.nbins[t], nblk = tab.nblk[t], E = tab.E[t];
    const int* __restrict__ src = tab.src[t];
    const int* __restrict__ dst = tab.dst[t];
    const float* __restrict__ ea = tab.ea[t];
    const int* sc = scanS + tab.moff[t];
    int tx = threadIdx.x;
    for (int i = tx; i < nbins; i += 256) { cnt[i] = 0; bas[i] = sc[i * nblk + lj]; }
    __syncthreads();
    int base = lj * CH + tx;
    for (int k0 = 0; k0 < 64; k0 += 4) {
        int d4[4], s4[4]; float w4[4];
#pragma unroll
        for (int k = 0; k < 4; ++k) {
            int e = base + (k0 + k) * 256;
            d4[k] = (e < E) ? dst[e] : -1;
            s4[k] = (e < E) ? src[e] : 0;
            w4[k] = (e < E) ? ea[e] : 0.f;
        }
#pragma unroll
        for (int k = 0; k < 4; ++k) {
            if (d4[k] >= 0) {
                int bl = d4[k] >> 10;
                int r = atomicAdd(&cnt[bl], 1);
                brec[bas[bl] + r] =
                    make_int2(((d4[k] & 1023) << 21) | s4[k], __float_as_int(w4[k]));
            }
        }
    }
}

__global__ void __launch_bounds__(256)
mcsr_k(BuildTab tab, const int2* __restrict__ brec, const int* __restrict__ scanS,
       int* __restrict__ starts, int2* __restrict__ poolG, int sbias)
{
    __shared__ int cnt[1024];
    __shared__ int lst[1024];
    __shared__ int sd[256];
    int b = blockIdx.x, t = 0;
    while (b >= tab.binBase[t + 1]) ++t;
    int bl = b - tab.binBase[t];
    int nblk = tab.nblk[t];
    int mo = tab.moff[t];
    int tx = threadIdx.x;
    int bs = scanS[mo + bl * nblk];
    int be = scanS[mo + (bl + 1) * nblk];
    for (int i = tx; i < 1024; i += 256) cnt[i] = 0;
    __syncthreads();
    int i = bs + tx;
    for (; i + 768 < be; i += 1024) {
        int2 r0 = brec[i], r1 = brec[i + 256], r2 = brec[i + 512], r3 = brec[i + 768];
        atomicAdd(&cnt[(unsigned)r0.x >> 21], 1);
        atomicAdd(&cnt[(unsigned)r1.x >> 21], 1);
        atomicAdd(&cnt[(unsigned)r2.x >> 21], 1);
        atomicAdd(&cnt[(unsigned)r3.x >> 21], 1);
    }
    for (; i < be; i += 256) atomicAdd(&cnt[(unsigned)brec[i].x >> 21], 1);
    __syncthreads();
    int v0 = cnt[tx * 4], v1 = cnt[tx * 4 + 1], v2 = cnt[tx * 4 + 2], v3 = cnt[tx * 4 + 3];
    int s0 = v0 + v1 + v2 + v3;
    sd[tx] = s0; __syncthreads();
    for (int off = 1; off < 256; off <<= 1) {
        int y = (tx >= off) ? sd[tx - off] : 0;
        __syncthreads();
        sd[tx] += y;
        __syncthreads();
    }
    int run = sd[tx] - s0;
    lst[tx * 4]     = run; run += v0;
    lst[tx * 4 + 1] = run; run += v1;
    lst[tx * 4 + 2] = run; run += v2;
    lst[tx * 4 + 3] = run;
    __syncthreads();
    int* startsSet = starts + tab.doff[t];
    int gb = sbias + bs;
    for (int q = tx; q < 1024; q += 256) startsSet[(bl << 10) + q] = gb + lst[q];
    for (int q = tx; q < 1024; q += 256) cnt[q] = 0;
    __syncthreads();
    i = bs + tx;
    for (; i < be; i += 256) {
        int2 rec = brec[i];
        int dl = (unsigned)rec.x >> 21;
        int r = atomicAdd(&cnt[dl], 1);
        poolG[bs + lst[dl] + r] = make_int2(rec.x & 0x1FFFFF, rec.y);
    }
}

// ---------------- scans (alias-safe for in-place use) ----------
__global__ void __launch_bounds__(256)
scan1_k(const int* deg, int* starts, int* part, int n)
{
    __shared__ int sd[256];
    int t = threadIdx.x;
    int base = blockIdx.x * SCHUNK + t * 32;
    int v[32]; int sum = 0;
#pragma unroll
    for (int k = 0; k < 32; ++k) { int i = base + k; v[k] = (i < n) ? deg[i] : 0; sum += v[k]; }
    sd[t] = sum; __syncthreads();
    for (int off = 1; off < 256; off <<= 1) {
        int y = (t >= off) ? sd[t - off] : 0;
        __syncthreads();
        sd[t] += y;
        __syncthreads();
    }
    int run = sd[t] - sum;
#pragma unroll
    for (int k = 0; k < 32; ++k) { int i = base + k; if (i < n) starts[i] = run; run += v[k]; }
    if (t == 255) part[blockIdx.x] = sd[255];
}

__global__ void __launch_bounds__(1024)
scan2_k(int* __restrict__ part, int nb)
{
    __shared__ int sd[1024];
    int t = threadIdx.x;
    int v = (t < nb) ? part[t] : 0;
    sd[t] = v; __syncthreads();
    for (int off = 1; off < 1024; off <<= 1) {
        int y = (t >= off) ? sd[t - off] : 0;
        __syncthreads();
        sd[t] += y;
        __syncthreads();
    }
    if (t < nb) part[t] = sd[t] - v;
}

__global__ void __launch_bounds__(256)
scan3_k(int* __restrict__ starts, const int* __restrict__ part, int n, int Etot)
{
    int i = blockIdx.x * 256 + threadIdx.x;
    if (i < n) starts[i] += part[i / SCHUNK];
    if (i == 0) starts[n] = Etot;
}

// ---------------- compute ----------------
template<int F>
DEV void row_fma(const float* __restrict__ p, float w, float* acc)
{
    static_assert(F % 4 == 0, "");
#pragma unroll
    for (int k = 0; k < F; k += 4) {
        float4 v = *reinterpret_cast<const float4*>(p + k);
        acc[k+0] = fmaf(w, v.x, acc[k+0]); acc[k+1] = fmaf(w, v.y, acc[k+1]);
        acc[k+2] = fmaf(w, v.z, acc[k+2]); acc[k+3] = fmaf(w, v.w, acc[k+3]);
    }
}

// Fused step 1+1.5: per face, gather cf (xc 8B rows), W_cf+b_cf+relu in regs,
// then t = [h12||xf] @ W_fp -> one aligned 64B row.
__global__ void __launch_bounds__(256)
cffp_k(const float* __restrict__ xc, const float* __restrict__ xf,
       const int2* __restrict__ ecsr, const int* __restrict__ starts,
       const float* __restrict__ W_cf, const float* __restrict__ b_cf,
       const float* __restrict__ W_fp, float* __restrict__ t, int n)
{
    __shared__ float sWcf[24];
    __shared__ float sbcf[12];
    __shared__ float sWfp[256];
    for (int i = threadIdx.x; i < 24;  i += 256) sWcf[i] = W_cf[i];
    for (int i = threadIdx.x; i < 12;  i += 256) sbcf[i] = b_cf[i];
    for (int i = threadIdx.x; i < 256; i += 256) sWfp[i] = W_fp[i];
    __syncthreads();
    int d = blockIdx.x * 256 + threadIdx.x;
    if (d >= n) return;
    int i0 = starts[d], i1 = starts[d + 1];
    float a0 = 0.f, a1 = 0.f;
    for (int i = i0; i < i1; ++i) {
        int2 rec = ecsr[i];
        float2 v = *reinterpret_cast<const float2*>(xc + (size_t)rec.x * 2);
        float w = __int_as_float(rec.y);
        a0 = fmaf(w, v.x, a0); a1 = fmaf(w, v.y, a1);
    }
    float h12[12];
#pragma unroll
    for (int j = 0; j < 12; ++j)
        h12[j] = fmaxf(fmaf(a0, sWcf[j], fmaf(a1, sWcf[12 + j], sbcf[j])), 0.f);
    float4 xfv = *reinterpret_cast<const float4*>(xf + (size_t)d * 4);
    float* op = t + (size_t)d * 16;
#pragma unroll
    for (int o = 0; o < 16; o += 4) {
        float4 y; float* yp = &y.x;
#pragma unroll
        for (int jj = 0; jj < 4; ++jj) {
            int oo = o + jj;
            float s =      xfv.x * sWfp[12 * 16 + oo];
            s = fmaf(xfv.y, sWfp[13 * 16 + oo], s);
            s = fmaf(xfv.z, sWfp[14 * 16 + oo], s);
            s = fmaf(xfv.w, sWfp[15 * 16 + oo], s);
#pragma unroll
            for (int j = 0; j < 12; ++j) s = fmaf(h12[j], sWfp[j * 16 + oo], s);
            yp[jj] = s;
        }
        *reinterpret_cast<float4*>(op + o) = y;
    }
}

template<int F, bool EPI>
__global__ void __launch_bounds__(256)
gather_sw_k(const float* __restrict__ x, const int2* __restrict__ ecsr,
            const int* __restrict__ starts, const float* __restrict__ b,
            float* __restrict__ out, int n)
{
    int d = blockIdx.x * 256 + threadIdx.x;
    if (d >= n) return;
    int i0 = starts[d], i1 = starts[d + 1];
    float acc[F];
#pragma unroll
    for (int k = 0; k < F; ++k) acc[k] = 0.f;
    for (int i = i0; i < i1; ++i) {
        int2 rec = ecsr[i];
        row_fma<F>(x + (size_t)rec.x * F, __int_as_float(rec.y), acc);
    }
    if constexpr (EPI) {
#pragma unroll
        for (int k = 0; k < F; ++k) acc[k] = fmaxf(acc[k] + b[k], 0.f);
    }
    float* op = out + (size_t)d * F;
#pragma unroll
    for (int k = 0; k < F; k += 4)
        *reinterpret_cast<float4*>(op + k) = make_float4(acc[k], acc[k+1], acc[k+2], acc[k+3]);
}

template<int FI1, int FI2, int FO>
__global__ void __launch_bounds__(256)
gather_conv_k(const float* __restrict__ x1, const float* __restrict__ x2,
              const int2* __restrict__ ecsr, const int* __restrict__ starts,
              const float* __restrict__ W, const float* __restrict__ b,
              float* __restrict__ out, int n)
{
    constexpr int FI = FI1 + FI2;
    __shared__ float sW[FI * FO];
    for (int i = threadIdx.x; i < FI * FO; i += 256) sW[i] = W[i];
    __syncthreads();
    int d = blockIdx.x * 256 + threadIdx.x;
    if (d >= n) return;
    int i0 = starts[d], i1 = starts[d + 1];
    float acc[FI];
#pragma unroll
    for (int k = 0; k < FI; ++k) acc[k] = 0.f;
    for (int i = i0; i < i1; ++i) {
        int2 rec = ecsr[i];
        float w = __int_as_float(rec.y);
        row_fma<FI1>(x1 + (size_t)rec.x * FI1, w, acc);
        if constexpr (FI2 > 0)
            row_fma<FI2>(x2 + (size_t)rec.x * FI2, w, acc + FI1);
    }
    float* op = out + (size_t)d * FO;
#pragma unroll
    for (int fo = 0; fo < FO; fo += 4) {
        float4 y; float* yp = &y.x;
#pragma unroll
        for (int j = 0; j < 4; ++j) {
            float s = b[fo + j];
#pragma unroll
            for (int k = 0; k < FI; ++k) s = fmaf(acc[k], sW[k * FO + fo + j], s);
            yp[j] = fmaxf(s, 0.f);
        }
        *reinterpret_cast<float4*>(op + fo) = y;
    }
}

// Fused gather + dense: acc = gather(F1) [optionally relu(acc+bpre)];
// out = [acc || x2[d]] @ W (no epilogue bias/relu — applied downstream).
template<int F1, int F2, int FO, bool EPIB>
__global__ void __launch_bounds__(256)
gather_dense_k(const float* __restrict__ x, const float* __restrict__ x2,
               const int2* __restrict__ ecsr, const int* __restrict__ starts,
               const float* __restrict__ bpre, const float* __restrict__ W,
               float* __restrict__ out, int n)
{
    constexpr int FI = F1 + F2;
    __shared__ float sW[FI * FO];
    for (int i = threadIdx.x; i < FI * FO; i += 256) sW[i] = W[i];
    __syncthreads();
    int d = blockIdx.x * 256 + threadIdx.x;
    if (d >= n) return;
    int i0 = starts[d], i1 = starts[d + 1];
    float acc[F1];
#pragma unroll
    for (int k = 0; k < F1; ++k) acc[k] = 0.f;
    for (int i = i0; i < i1; ++i) {
        int2 rec = ecsr[i];
        row_fma<F1>(x + (size_t)rec.x * F1, __int_as_float(rec.y), acc);
    }
    if constexpr (EPIB) {
#pragma unroll
        for (int k = 0; k < F1; ++k) acc[k] = fmaxf(acc[k] + bpre[k], 0.f);
    }
    float xin2[F2 > 0 ? F2 : 1];
    if constexpr (F2 > 0) {
        const float* p = x2 + (size_t)d * F2;
#pragma unroll
        for (int k = 0; k < F2; k += 4) {
            float4 v = *reinterpret_cast<const float4*>(p + k);
            xin2[k] = v.x; xin2[k+1] = v.y; xin2[k+2] = v.z; xin2[k+3] = v.w;
        }
    }
    float* op = out + (size_t)d * FO;
#pragma unroll
    for (int fo = 0; fo < FO; fo += 4) {
        float4 y; float* yp = &y.x;
#pragma unroll
        for (int j = 0; j < 4; ++j) {
            float s = 0.f;
#pragma unroll
            for (int k = 0; k < F1; ++k) s = fmaf(acc[k], sW[k * FO + fo + j], s);
            if constexpr (F2 > 0)
#pragma unroll
                for (int k = 0; k < F2; ++k) s = fmaf(xin2[k], sW[(F1 + k) * FO + fo + j], s);
            yp[j] = s;
        }
        *reinterpret_cast<float4*>(op + fo) = y;
    }
}

__global__ void __launch_bounds__(256)
gather_final_k(const float* __restrict__ x, const int2* __restrict__ ecsr,
               const int* __restrict__ starts, const float* __restrict__ b9b,
               const float* __restrict__ Wf, const float* __restrict__ bf,
               float* __restrict__ out, int n)
{
    int d = blockIdx.x * 256 + threadIdx.x;
    if (d >= n) return;
    int i0 = starts[d], i1 = starts[d + 1];
    float acc[16];
#pragma unroll
    for (int k = 0; k < 16; ++k) acc[k] = 0.f;
    for (int i = i0; i < i1; ++i) {
        int2 rec = ecsr[i];
        row_fma<16>(x + (size_t)rec.x * 16, __int_as_float(rec.y), acc);
    }
    float y = bf[0];
#pragma unroll
    for (int k = 0; k < 16; ++k) y = fmaf(fmaxf(acc[k] + b9b[k], 0.f), Wf[k], y);
    out[d] = y;
}

// ---------------- host ----------------
extern "C" void kernel_launch(void* const* d_in, const int* in_sizes, int n_in,
                              void* d_out, int out_size, void* d_ws, size_t ws_size,
                              hipStream_t stream)
{
    const float* xc = (const float*)d_in[0];
    const float* xf = (const float*)d_in[1];

    auto SRC = [&](int i) { return (const int*)d_in[i]; };
    auto DST = [&](int i) { return (const int*)d_in[i] + in_sizes[i] / 2; };
    auto EA  = [&](int i) { return (const float*)d_in[i + 1]; };
    auto EN  = [&](int i) { return in_sizes[i] / 2; };

    const float* W_cf=(const float*)d_in[34]; const float* b_cf=(const float*)d_in[35];
    const float* W_fp=(const float*)d_in[36]; const float* b_fp=(const float*)d_in[37];
    const float* W2  =(const float*)d_in[38]; const float* b2  =(const float*)d_in[39];
    const float* W3  =(const float*)d_in[40]; const float* b3  =(const float*)d_in[41];
    const float* W4  =(const float*)d_in[42]; const float* b4  =(const float*)d_in[43];
    const float* W5a =(const float*)d_in[44]; const float* b5a =(const float*)d_in[45];
    const float* W5b =(const float*)d_in[46]; const float* b5b =(const float*)d_in[47];
    const float* W6  =(const float*)d_in[48]; const float* b6  =(const float*)d_in[49];
    const float* W7  =(const float*)d_in[50]; const float* b7  =(const float*)d_in[51];
    const float* W8  =(const float*)d_in[52]; const float* b8  =(const float*)d_in[53];
    const float* W9a =(const float*)d_in[54]; const float* b9a =(const float*)d_in[55];
    const float* W9b =(const float*)d_in[56]; const float* b9b =(const float*)d_in[57];
    const float* Wf  =(const float*)d_in[58]; const float* bfb =(const float*)d_in[59];

    float* ws = (float*)d_ws;
    auto pad4 = [](size_t x) { return (x + 3) & ~(size_t)3; };
    auto nbinsOf = [](int nd) { return (nd + 1023) >> 10; };

    const int sI_in[2]  = {2, 4};
    const int sI_nd[2]  = {NFc, N0c};
    const int sII_in[14] = {6, 8, 10, 12, 14, 16, 18, 20, 22, 24, 26, 28, 30, 32};
    const int sII_nd[14] = {NCc, N0c, N1c, N2c, N3c, N4c, N1c, N2c, N3c, N4c,
                            N0c, N1c, N2c, N3c};

    // ---- zone sizing (4B units); node ranges padded to 1024 per set ----
    size_t sumNdPadI = 0, sumEI = 0, sumNdPadII = 0, sumEII = 0;
    for (int t = 0; t < 2;  ++t) { sumNdPadI  += (size_t)nbinsOf(sI_nd[t])  << 10; sumEI  += EN(sI_in[t]); }
    for (int t = 0; t < 14; ++t) { sumNdPadII += (size_t)nbinsOf(sII_nd[t]) << 10; sumEII += EN(sII_in[t]); }
    size_t zI  = pad4(sumNdPadI  + 1) + pad4(2 * sumEI);
    size_t zII = pad4(sumNdPadII + 1) + pad4(2 * sumEII);
    size_t zAB = (zI > zII) ? zI : zII;
    size_t zD_o   = zAB;
    size_t part_o = zD_o + ZDCAP;
    size_t zC_o   = part_o + 1024;
    size_t t_o    = zI;          // fp pre-transform scratch (Stage I only)

    int* part = (int*)(ws + part_o);
    const int B = 256;
    auto G = [&](int n) { return dim3((unsigned)((n + B - 1) / B)); };

    // Fused multi-set bucketed build: per group {mhist, scan1/2/3, mscat,
    // mcsr} = 6 launches (was 3*nsets+3).
    auto buildStage = [&](int ns, const int* sin, const int* snd,
                          int* starts, int2* pool, int* doffOut) {
        int nbinsA[14], nblkA[14];
        long long eoffA[14];
        long long sumNdPad = 0, sumE = 0;
        for (int t = 0; t < ns; ++t) {
            int nd = snd[t], E = EN(sin[t]);
            doffOut[t] = (int)sumNdPad;
            nbinsA[t] = (nd + 1023) >> 10;
            sumNdPad += (long long)nbinsA[t] << 10;
            nblkA[t] = (E + CH - 1) / CH;
            eoffA[t] = sumE;
            sumE += E;
        }
        int t0 = 0;
        while (t0 < ns) {
            long long cost = 0; int t1 = t0;
            while (t1 < ns) {
                long long c = 2LL * EN(sin[t1]) + (long long)nbinsA[t1] * nblkA[t1];
                if (t1 > t0 && cost + c + 1 > (long long)ZDCAP) break;
                cost += c; ++t1;
            }
            BuildTab tb{};
            int gn = t1 - t0, tc = 0, tbn = 0, maxNb = 0;
            long long LA = 0, gE = 0;
            for (int t = t0; t < t1; ++t) {
                int q = t - t0;
                tb.src[q] = SRC(sin[t]); tb.dst[q] = DST(sin[t]); tb.ea[q] = EA(sin[t]);
                tb.chunkBase[q] = tc; tb.binBase[q] = tbn;
                tb.moff[q] = (int)LA; tb.doff[q] = doffOut[t];
                tb.E[q] = EN(sin[t]); tb.nblk[q] = nblkA[t]; tb.nbins[q] = nbinsA[t];
                tc += nblkA[t]; tbn += nbinsA[t];
                LA += (long long)nbinsA[t] * nblkA[t]; gE += EN(sin[t]);
                if (nbinsA[t] > maxNb) maxNb = nbinsA[t];
            }
            tb.chunkBase[gn] = tc; tb.binBase[gn] = tbn; tb.nsets = gn;
            int2* brec = (int2*)(ws + zD_o);
            int*  hist = (int*)(ws + zD_o) + 2 * gE;
            if (maxNb > 1024)
                mhist_k<2048><<<dim3((unsigned)tc), B, 0, stream>>>(tb, hist);
            else
                mhist_k<1024><<<dim3((unsigned)tc), B, 0, stream>>>(tb, hist);
            int nb = (int)((LA + SCHUNK - 1) / SCHUNK);
            scan1_k<<<dim3((unsigned)nb), B, 0, stream>>>(hist, hist, part, (int)LA);
            scan2_k<<<dim3(1), 1024, 0, stream>>>(part, nb);
            scan3_k<<<G((int)LA + 1), B, 0, stream>>>(hist, part, (int)LA, (int)gE);
            if (maxNb > 1024)
                mscat_k<2048><<<dim3((unsigned)tc), B, 0, stream>>>(tb, hist, brec);
            else
                mscat_k<1024><<<dim3((unsigned)tc), B, 0, stream>>>(tb, hist, brec);
            long long gBase = eoffA[t0];
            mcsr_k<<<dim3((unsigned)tbn), B, 0, stream>>>(
                tb, brec, hist, starts, pool + gBase, (int)gBase);
            t0 = t1;
        }
    };

    // ---- feature buffers ----
    float* t   = ws + t_o;                   // [NF,16] fp pre-transform, 1-2
    float* c1  = ws + zC_o;                  // [N0,16], steps 2-18 (tail zone)
    float* tpc = c1;                         // steps 19.5-21 (c1 dead)
    size_t mb = zD_o;
    auto mal = [&](size_t n) { size_t o = mb; mb += pad4(n); return ws + o; };
    float* p1  = mal((size_t)N1c*16);
    float* c2  = mal((size_t)N1c*16);
    float* p2  = mal((size_t)N2c*16);
    float* c3  = mal((size_t)N2c*16);
    float* p3  = mal((size_t)N3c*16);
    float* c4  = mal((size_t)N3c*32);
    float* p4  = mal((size_t)N4c*32);
    float* c5a = mal((size_t)N4c*32);
    float* c5b = mal((size_t)N4c*32);
    float* t6  = mal((size_t)N3c*32);
    float* g6  = mal((size_t)N3c*32);
    float* t7  = mal((size_t)N2c*32);
    float* g7  = mal((size_t)N2c*32);
    float* t8  = mal((size_t)N1c*16);
    float* g8  = mal((size_t)N1c*16);        // arena ends ~zD_o+12.06M <= ZDCAP
    // t9 OVERLAYS zD_o[0,8M): at step 18 all mids below g8's 10.06M offset
    // are dead (p1..t8); g8 [10.06M,12.06M) and c1 (tail zone) are disjoint.
    float* t9  = ws + zD_o;
    float* out = (float*)d_out;

    // ---- Stage I: cf+fp CSRs (one group) + steps 1-2 ----
    int* startsI = (int*)(ws + 0);
    int2* poolI  = (int2*)(ws + pad4(sumNdPadI + 1));
    int doffI[2];
    buildStage(2, sI_in, sI_nd, startsI, poolI, doffI);
    // 1) fused: h = relu(gather(cf,xc)@W_cf+b_cf); t = [h||xf]@W_fp  [NF,16]
    cffp_k<<<G(NFc), B, 0, stream>>>(
        xc, xf, poolI, startsI + doffI[0], W_cf, b_cf, W_fp, t, NFc);
    // 2) c1 = relu(gather(fp, t) + b_fp)                       [N0,16]
    gather_sw_k<16,true><<<G(N0c), B, 0, stream>>>(
        t, poolI, startsI + doffI[1], b_fp, c1, N0c);

    // ---- Stage II: 14 remaining CSRs (2 groups; t dead) ----
    int* startsII = (int*)(ws + 0);
    int2* poolII  = (int2*)(ws + pad4(sumNdPadII + 1));
    int doffII[14];
    buildStage(14, sII_in, sII_nd, startsII, poolII, doffII);
    enum { f_pc, f_pp0, f_pp1, f_pp2, f_pp3, f_pp4, f_po0, f_po1, f_po2, f_po3,
           f_up0, f_up1, f_up2, f_up3 };
    auto st = [&](int t_) { return startsII + doffII[t_]; };
    int2* ec = poolII;

    // ---- Stage III: pipeline ----
    // 3) p1 = gather(pool0, c1)
    gather_sw_k<16,false><<<G(N1c), B, 0, stream>>>(c1, ec, st(f_po0), nullptr, p1, N1c);
    // 4) c2
    gather_conv_k<16,0,16><<<G(N1c), B, 0, stream>>>(p1, nullptr, ec, st(f_pp1), W2, b2, c2, N1c);
    // 5) p2
    gather_sw_k<16,false><<<G(N2c), B, 0, stream>>>(c2, ec, st(f_po1), nullptr, p2, N2c);
    // 6) c3
    gather_conv_k<16,0,16><<<G(N2c), B, 0, stream>>>(p2, nullptr, ec, st(f_pp2), W3, b3, c3, N2c);
    // 7) p3
    gather_sw_k<16,false><<<G(N3c), B, 0, stream>>>(c3, ec, st(f_po2), nullptr, p3, N3c);
    // 8) c4
    gather_conv_k<16,0,32><<<G(N3c), B, 0, stream>>>(p3, nullptr, ec, st(f_pp3), W4, b4, c4, N3c);
    // 9) p4
    gather_sw_k<32,false><<<G(N4c), B, 0, stream>>>(c4, ec, st(f_po3), nullptr, p4, N4c);
    // 10) c5a
    gather_conv_k<32,0,32><<<G(N4c), B, 0, stream>>>(p4, nullptr, ec, st(f_pp4), W5a, b5a, c5a, N4c);
    // 11) c5b
    gather_conv_k<32,0,32><<<G(N4c), B, 0, stream>>>(c5a, nullptr, ec, st(f_pp4), W5b, b5b, c5b, N4c);
    // 12+13a) t6 = [gather(unpool3, c5b) || c4] @ W6
    gather_dense_k<32,32,32,false><<<G(N3c), B, 0, stream>>>(
        c5b, c4, ec, st(f_up3), nullptr, W6, t6, N3c);
    // 13b) g6 = relu(gather(pp3, t6) + b6)
    gather_sw_k<32,true><<<G(N3c), B, 0, stream>>>(t6, ec, st(f_pp3), b6, g6, N3c);
    // 14+15a) t7 = [gather(unpool2, g6) || c3] @ W7
    gather_dense_k<32,16,32,false><<<G(N2c), B, 0, stream>>>(
        g6, c3, ec, st(f_up2), nullptr, W7, t7, N2c);
    // 15b) g7
    gather_sw_k<32,true><<<G(N2c), B, 0, stream>>>(t7, ec, st(f_pp2), b7, g7, N2c);
    // 16+17a) t8 = [gather(unpool1, g7) || c2] @ W8
    gather_dense_k<32,16,16,false><<<G(N1c), B, 0, stream>>>(
        g7, c2, ec, st(f_up1), nullptr, W8, t8, N1c);
    // 17b) g8
    gather_sw_k<16,true><<<G(N1c), B, 0, stream>>>(t8, ec, st(f_pp1), b8, g8, N1c);
    // 18+19a) t9 = [gather(unpool0, g8) || c1] @ W9a   (t9 overlays dead mids)
    gather_dense_k<16,16,16,false><<<G(N0c), B, 0, stream>>>(
        g8, c1, ec, st(f_up0), nullptr, W9a, t9, N0c);
    // 19b+20) tpc = relu(gather(pp0, t9) + b9a) @ W9b   (overlays c1)
    gather_dense_k<16,0,16,true><<<G(N0c), B, 0, stream>>>(
        t9, nullptr, ec, st(f_pp0), b9a, W9b, tpc, N0c);
    // 21) fused pc gather + bias + relu + Wf dot
    gather_final_k<<<G(NCc), B, 0, stream>>>(tpc, ec, st(f_pc), b9b, Wf, bfb, out, NCc);
}

// Round 6
// 1512.619 us; speedup vs baseline: 1.6055x; 1.0704x over previous
//
#include <hip/hip_runtime.h>
#include <cstdint>
#include <cstddef>

// ---------------------------------------------------------------------------
// GraphUNetSmall, round 11: build kernels were parallelism-starved.
//
// R10 post-mortem: mscat_k g1 = 164us at Occupancy 19%, HBM 20%, VALU 2.5%.
// Grid 529 blocks x 4 waves = 2116 waves = 26% of machine even if packed —
// latency-bound by construction. Fix: 1024 threads/block for mhist/mscat/
// mcsr (529 x 16 waves ~= full machine). CH stays 16384 so the memory plan,
// run lengths, hist matrix, and ZDCAP grouping are untouched; per-thread
// edge counts drop 4x. mcsr's 1024-bin scan becomes one-bin-per-thread.
// Record content/layout identical; only within-node insertion order shifts
// (already nondeterministic via atomics).
// ---------------------------------------------------------------------------

#define DEV __device__ __forceinline__

static constexpr int NCc = 1000000;
static constexpr int NFc = 1500000;
static constexpr int N0c = 500000;
static constexpr int N1c = 125000;
static constexpr int N2c = 31250;
static constexpr int N3c = 7813;
static constexpr int N4c = 1954;
static constexpr int SCHUNK = 8192;   // elems per scan block (256 thr * 32)
static constexpr int CH = 16384;      // edges per bucket-build block
static constexpr size_t ZDCAP = 17690000;  // ZoneD capacity, 4B units

// Per-group set table for the fused build kernels (kernarg, <=4KB).
struct BuildTab {
    const int*   src[14];
    const int*   dst[14];
    const float* ea[14];
    int chunkBase[15];   // prefix of nblk
    int binBase[15];     // prefix of nbins
    int moff[14];        // matrix offset = prefix of nbins*nblk
    int doff[14];        // absolute starts-array offset of set
    int E[14];
    int nblk[14];
    int nbins[14];
    int nsets;
};

// ---------------- bucketed CSR build (zero global atomics) ----------------

// Phase 1a: per-block LDS histogram over 1024-node buckets, multi-set.
// 1024 threads, 16 edges/thread (8-deep load pipeline).
template<int NB>
__global__ void __launch_bounds__(1024)
mhist_k(BuildTab tab, int* __restrict__ histG)
{
    __shared__ int sh[NB];
    int j = blockIdx.x, t = 0;
    while (j >= tab.chunkBase[t + 1]) ++t;
    int lj = j - tab.chunkBase[t];
    int nbins = tab.nbins[t], nblk = tab.nblk[t], E = tab.E[t];
    const int* __restrict__ dst = tab.dst[t];
    int* hg = histG + tab.moff[t];
    int tx = threadIdx.x;
    for (int i = tx; i < nbins; i += 1024) sh[i] = 0;
    __syncthreads();
    int base = lj * CH + tx;
    for (int k0 = 0; k0 < 16; k0 += 8) {
        int d8[8];
#pragma unroll
        for (int k = 0; k < 8; ++k) {
            int e = base + (k0 + k) * 1024;
            d8[k] = (e < E) ? dst[e] : -1;
        }
#pragma unroll
        for (int k = 0; k < 8; ++k)
            if (d8[k] >= 0) atomicAdd(&sh[d8[k] >> 10], 1);
    }
    __syncthreads();
    for (int i = tx; i < nbins; i += 1024) hg[i * nblk + lj] = sh[i];
}

// Phase 1b: LDS-rank scatter of packed records (dlow<<21|src, ea) into
// bucket-contiguous regions, multi-set. src < 2^21 (max dim NF=1.5M).
// 1024 threads, 16 edges/thread (4-deep).
template<int NB>
__global__ void __launch_bounds__(1024)
mscat_k(BuildTab tab, const int* __restrict__ scanS, int2* __restrict__ brec)
{
    __shared__ int cnt[NB];
    __shared__ int bas[NB];
    int j = blockIdx.x, t = 0;
    while (j >= tab.chunkBase[t + 1]) ++t;
    int lj = j - tab.chunkBase[t];
    int nbins = tab.nbins[t], nblk = tab.nblk[t], E = tab.E[t];
    const int* __restrict__ src = tab.src[t];
    const int* __restrict__ dst = tab.dst[t];
    const float* __restrict__ ea = tab.ea[t];
    const int* sc = scanS + tab.moff[t];
    int tx = threadIdx.x;
    for (int i = tx; i < nbins; i += 1024) { cnt[i] = 0; bas[i] = sc[i * nblk + lj]; }
    __syncthreads();
    int base = lj * CH + tx;
    for (int k0 = 0; k0 < 16; k0 += 4) {
        int d4[4], s4[4]; float w4[4];
#pragma unroll
        for (int k = 0; k < 4; ++k) {
            int e = base + (k0 + k) * 1024;
            d4[k] = (e < E) ? dst[e] : -1;
            s4[k] = (e < E) ? src[e] : 0;
            w4[k] = (e < E) ? ea[e] : 0.f;
        }
#pragma unroll
        for (int k = 0; k < 4; ++k) {
            if (d4[k] >= 0) {
                int bl = d4[k] >> 10;
                int r = atomicAdd(&cnt[bl], 1);
                brec[bas[bl] + r] =
                    make_int2(((d4[k] & 1023) << 21) | s4[k], __float_as_int(w4[k]));
            }
        }
    }
}

// Phase 2: one block per bucket, multi-set, 1024 threads (one bin each).
// Records contiguous at [scanS[mo+bl*nblk], scanS[mo+(bl+1)*nblk]).
__global__ void __launch_bounds__(1024)
mcsr_k(BuildTab tab, const int2* __restrict__ brec, const int* __restrict__ scanS,
       int* __restrict__ starts, int2* __restrict__ poolG, int sbias)
{
    __shared__ int cnt[1024];
    __shared__ int lst[1024];
    __shared__ int sd[1024];
    int b = blockIdx.x, t = 0;
    while (b >= tab.binBase[t + 1]) ++t;
    int bl = b - tab.binBase[t];
    int nblk = tab.nblk[t];
    int mo = tab.moff[t];
    int tx = threadIdx.x;
    int bs = scanS[mo + bl * nblk];
    int be = scanS[mo + (bl + 1) * nblk];
    cnt[tx] = 0;
    __syncthreads();
    // pass A: per-node counts (4-deep)
    int i = bs + tx;
    for (; i + 3072 < be; i += 4096) {
        int2 r0 = brec[i], r1 = brec[i + 1024], r2 = brec[i + 2048], r3 = brec[i + 3072];
        atomicAdd(&cnt[(unsigned)r0.x >> 21], 1);
        atomicAdd(&cnt[(unsigned)r1.x >> 21], 1);
        atomicAdd(&cnt[(unsigned)r2.x >> 21], 1);
        atomicAdd(&cnt[(unsigned)r3.x >> 21], 1);
    }
    for (; i < be; i += 1024) atomicAdd(&cnt[(unsigned)brec[i].x >> 21], 1);
    __syncthreads();
    // exclusive scan, one bin per thread
    int v = cnt[tx];
    sd[tx] = v; __syncthreads();
    for (int off = 1; off < 1024; off <<= 1) {
        int y = (tx >= off) ? sd[tx - off] : 0;
        __syncthreads();
        sd[tx] += y;
        __syncthreads();
    }
    lst[tx] = sd[tx] - v;
    __syncthreads();
    int* startsSet = starts + tab.doff[t];
    int gb = sbias + bs;
    startsSet[(bl << 10) + tx] = gb + lst[tx];
    cnt[tx] = 0;
    __syncthreads();
    // pass B: scatter into final CSR pool (cursor = zeroed cnt)
    i = bs + tx;
    for (; i < be; i += 1024) {
        int2 rec = brec[i];
        int dl = (unsigned)rec.x >> 21;
        int r = atomicAdd(&cnt[dl], 1);
        poolG[bs + lst[dl] + r] = make_int2(rec.x & 0x1FFFFF, rec.y);
    }
}

// ---------------- scans (alias-safe for in-place use) ----------
__global__ void __launch_bounds__(256)
scan1_k(const int* deg, int* starts, int* part, int n)
{
    __shared__ int sd[256];
    int t = threadIdx.x;
    int base = blockIdx.x * SCHUNK + t * 32;
    int v[32]; int sum = 0;
#pragma unroll
    for (int k = 0; k < 32; ++k) { int i = base + k; v[k] = (i < n) ? deg[i] : 0; sum += v[k]; }
    sd[t] = sum; __syncthreads();
    for (int off = 1; off < 256; off <<= 1) {
        int y = (t >= off) ? sd[t - off] : 0;
        __syncthreads();
        sd[t] += y;
        __syncthreads();
    }
    int run = sd[t] - sum;
#pragma unroll
    for (int k = 0; k < 32; ++k) { int i = base + k; if (i < n) starts[i] = run; run += v[k]; }
    if (t == 255) part[blockIdx.x] = sd[255];
}

__global__ void __launch_bounds__(1024)
scan2_k(int* __restrict__ part, int nb)
{
    __shared__ int sd[1024];
    int t = threadIdx.x;
    int v = (t < nb) ? part[t] : 0;
    sd[t] = v; __syncthreads();
    for (int off = 1; off < 1024; off <<= 1) {
        int y = (t >= off) ? sd[t - off] : 0;
        __syncthreads();
        sd[t] += y;
        __syncthreads();
    }
    if (t < nb) part[t] = sd[t] - v;
}

__global__ void __launch_bounds__(256)
scan3_k(int* __restrict__ starts, const int* __restrict__ part, int n, int Etot)
{
    int i = blockIdx.x * 256 + threadIdx.x;
    if (i < n) starts[i] += part[i / SCHUNK];
    if (i == 0) starts[n] = Etot;
}

// ---------------- compute ----------------
template<int F>
DEV void row_fma(const float* __restrict__ p, float w, float* acc)
{
    static_assert(F % 4 == 0, "");
#pragma unroll
    for (int k = 0; k < F; k += 4) {
        float4 v = *reinterpret_cast<const float4*>(p + k);
        acc[k+0] = fmaf(w, v.x, acc[k+0]); acc[k+1] = fmaf(w, v.y, acc[k+1]);
        acc[k+2] = fmaf(w, v.z, acc[k+2]); acc[k+3] = fmaf(w, v.w, acc[k+3]);
    }
}

// Fused step 1+1.5: per face, gather cf (xc 8B rows), W_cf+b_cf+relu in regs,
// then t = [h12||xf] @ W_fp -> one aligned 64B row.
__global__ void __launch_bounds__(256)
cffp_k(const float* __restrict__ xc, const float* __restrict__ xf,
       const int2* __restrict__ ecsr, const int* __restrict__ starts,
       const float* __restrict__ W_cf, const float* __restrict__ b_cf,
       const float* __restrict__ W_fp, float* __restrict__ t, int n)
{
    __shared__ float sWcf[24];
    __shared__ float sbcf[12];
    __shared__ float sWfp[256];
    for (int i = threadIdx.x; i < 24;  i += 256) sWcf[i] = W_cf[i];
    for (int i = threadIdx.x; i < 12;  i += 256) sbcf[i] = b_cf[i];
    for (int i = threadIdx.x; i < 256; i += 256) sWfp[i] = W_fp[i];
    __syncthreads();
    int d = blockIdx.x * 256 + threadIdx.x;
    if (d >= n) return;
    int i0 = starts[d], i1 = starts[d + 1];
    float a0 = 0.f, a1 = 0.f;
    for (int i = i0; i < i1; ++i) {
        int2 rec = ecsr[i];
        float2 v = *reinterpret_cast<const float2*>(xc + (size_t)rec.x * 2);
        float w = __int_as_float(rec.y);
        a0 = fmaf(w, v.x, a0); a1 = fmaf(w, v.y, a1);
    }
    float h12[12];
#pragma unroll
    for (int j = 0; j < 12; ++j)
        h12[j] = fmaxf(fmaf(a0, sWcf[j], fmaf(a1, sWcf[12 + j], sbcf[j])), 0.f);
    float4 xfv = *reinterpret_cast<const float4*>(xf + (size_t)d * 4);
    float* op = t + (size_t)d * 16;
#pragma unroll
    for (int o = 0; o < 16; o += 4) {
        float4 y; float* yp = &y.x;
#pragma unroll
        for (int jj = 0; jj < 4; ++jj) {
            int oo = o + jj;
            float s =      xfv.x * sWfp[12 * 16 + oo];
            s = fmaf(xfv.y, sWfp[13 * 16 + oo], s);
            s = fmaf(xfv.z, sWfp[14 * 16 + oo], s);
            s = fmaf(xfv.w, sWfp[15 * 16 + oo], s);
#pragma unroll
            for (int j = 0; j < 12; ++j) s = fmaf(h12[j], sWfp[j * 16 + oo], s);
            yp[jj] = s;
        }
        *reinterpret_cast<float4*>(op + o) = y;
    }
}

template<int F, bool EPI>
__global__ void __launch_bounds__(256)
gather_sw_k(const float* __restrict__ x, const int2* __restrict__ ecsr,
            const int* __restrict__ starts, const float* __restrict__ b,
            float* __restrict__ out, int n)
{
    int d = blockIdx.x * 256 + threadIdx.x;
    if (d >= n) return;
    int i0 = starts[d], i1 = starts[d + 1];
    float acc[F];
#pragma unroll
    for (int k = 0; k < F; ++k) acc[k] = 0.f;
    for (int i = i0; i < i1; ++i) {
        int2 rec = ecsr[i];
        row_fma<F>(x + (size_t)rec.x * F, __int_as_float(rec.y), acc);
    }
    if constexpr (EPI) {
#pragma unroll
        for (int k = 0; k < F; ++k) acc[k] = fmaxf(acc[k] + b[k], 0.f);
    }
    float* op = out + (size_t)d * F;
#pragma unroll
    for (int k = 0; k < F; k += 4)
        *reinterpret_cast<float4*>(op + k) = make_float4(acc[k], acc[k+1], acc[k+2], acc[k+3]);
}

template<int FI1, int FI2, int FO>
__global__ void __launch_bounds__(256)
gather_conv_k(const float* __restrict__ x1, const float* __restrict__ x2,
              const int2* __restrict__ ecsr, const int* __restrict__ starts,
              const float* __restrict__ W, const float* __restrict__ b,
              float* __restrict__ out, int n)
{
    constexpr int FI = FI1 + FI2;
    __shared__ float sW[FI * FO];
    for (int i = threadIdx.x; i < FI * FO; i += 256) sW[i] = W[i];
    __syncthreads();
    int d = blockIdx.x * 256 + threadIdx.x;
    if (d >= n) return;
    int i0 = starts[d], i1 = starts[d + 1];
    float acc[FI];
#pragma unroll
    for (int k = 0; k < FI; ++k) acc[k] = 0.f;
    for (int i = i0; i < i1; ++i) {
        int2 rec = ecsr[i];
        float w = __int_as_float(rec.y);
        row_fma<FI1>(x1 + (size_t)rec.x * FI1, w, acc);
        if constexpr (FI2 > 0)
            row_fma<FI2>(x2 + (size_t)rec.x * FI2, w, acc + FI1);
    }
    float* op = out + (size_t)d * FO;
#pragma unroll
    for (int fo = 0; fo < FO; fo += 4) {
        float4 y; float* yp = &y.x;
#pragma unroll
        for (int j = 0; j < 4; ++j) {
            float s = b[fo + j];
#pragma unroll
            for (int k = 0; k < FI; ++k) s = fmaf(acc[k], sW[k * FO + fo + j], s);
            yp[j] = fmaxf(s, 0.f);
        }
        *reinterpret_cast<float4*>(op + fo) = y;
    }
}

// Fused gather + dense: acc = gather(F1) [optionally relu(acc+bpre)];
// out = [acc || x2[d]] @ W (no epilogue bias/relu — applied downstream).
template<int F1, int F2, int FO, bool EPIB>
__global__ void __launch_bounds__(256)
gather_dense_k(const float* __restrict__ x, const float* __restrict__ x2,
               const int2* __restrict__ ecsr, const int* __restrict__ starts,
               const float* __restrict__ bpre, const float* __restrict__ W,
               float* __restrict__ out, int n)
{
    constexpr int FI = F1 + F2;
    __shared__ float sW[FI * FO];
    for (int i = threadIdx.x; i < FI * FO; i += 256) sW[i] = W[i];
    __syncthreads();
    int d = blockIdx.x * 256 + threadIdx.x;
    if (d >= n) return;
    int i0 = starts[d], i1 = starts[d + 1];
    float acc[F1];
#pragma unroll
    for (int k = 0; k < F1; ++k) acc[k] = 0.f;
    for (int i = i0; i < i1; ++i) {
        int2 rec = ecsr[i];
        row_fma<F1>(x + (size_t)rec.x * F1, __int_as_float(rec.y), acc);
    }
    if constexpr (EPIB) {
#pragma unroll
        for (int k = 0; k < F1; ++k) acc[k] = fmaxf(acc[k] + bpre[k], 0.f);
    }
    float xin2[F2 > 0 ? F2 : 1];
    if constexpr (F2 > 0) {
        const float* p = x2 + (size_t)d * F2;
#pragma unroll
        for (int k = 0; k < F2; k += 4) {
            float4 v = *reinterpret_cast<const float4*>(p + k);
            xin2[k] = v.x; xin2[k+1] = v.y; xin2[k+2] = v.z; xin2[k+3] = v.w;
        }
    }
    float* op = out + (size_t)d * FO;
#pragma unroll
    for (int fo = 0; fo < FO; fo += 4) {
        float4 y; float* yp = &y.x;
#pragma unroll
        for (int j = 0; j < 4; ++j) {
            float s = 0.f;
#pragma unroll
            for (int k = 0; k < F1; ++k) s = fmaf(acc[k], sW[k * FO + fo + j], s);
            if constexpr (F2 > 0)
#pragma unroll
                for (int k = 0; k < F2; ++k) s = fmaf(xin2[k], sW[(F1 + k) * FO + fo + j], s);
            yp[j] = s;
        }
        *reinterpret_cast<float4*>(op + fo) = y;
    }
}

__global__ void __launch_bounds__(256)
gather_final_k(const float* __restrict__ x, const int2* __restrict__ ecsr,
               const int* __restrict__ starts, const float* __restrict__ b9b,
               const float* __restrict__ Wf, const float* __restrict__ bf,
               float* __restrict__ out, int n)
{
    int d = blockIdx.x * 256 + threadIdx.x;
    if (d >= n) return;
    int i0 = starts[d], i1 = starts[d + 1];
    float acc[16];
#pragma unroll
    for (int k = 0; k < 16; ++k) acc[k] = 0.f;
    for (int i = i0; i < i1; ++i) {
        int2 rec = ecsr[i];
        row_fma<16>(x + (size_t)rec.x * 16, __int_as_float(rec.y), acc);
    }
    float y = bf[0];
#pragma unroll
    for (int k = 0; k < 16; ++k) y = fmaf(fmaxf(acc[k] + b9b[k], 0.f), Wf[k], y);
    out[d] = y;
}

// ---------------- host ----------------
extern "C" void kernel_launch(void* const* d_in, const int* in_sizes, int n_in,
                              void* d_out, int out_size, void* d_ws, size_t ws_size,
                              hipStream_t stream)
{
    const float* xc = (const float*)d_in[0];
    const float* xf = (const float*)d_in[1];

    auto SRC = [&](int i) { return (const int*)d_in[i]; };
    auto DST = [&](int i) { return (const int*)d_in[i] + in_sizes[i] / 2; };
    auto EA  = [&](int i) { return (const float*)d_in[i + 1]; };
    auto EN  = [&](int i) { return in_sizes[i] / 2; };

    const float* W_cf=(const float*)d_in[34]; const float* b_cf=(const float*)d_in[35];
    const float* W_fp=(const float*)d_in[36]; const float* b_fp=(const float*)d_in[37];
    const float* W2  =(const float*)d_in[38]; const float* b2  =(const float*)d_in[39];
    const float* W3  =(const float*)d_in[40]; const float* b3  =(const float*)d_in[41];
    const float* W4  =(const float*)d_in[42]; const float* b4  =(const float*)d_in[43];
    const float* W5a =(const float*)d_in[44]; const float* b5a =(const float*)d_in[45];
    const float* W5b =(const float*)d_in[46]; const float* b5b =(const float*)d_in[47];
    const float* W6  =(const float*)d_in[48]; const float* b6  =(const float*)d_in[49];
    const float* W7  =(const float*)d_in[50]; const float* b7  =(const float*)d_in[51];
    const float* W8  =(const float*)d_in[52]; const float* b8  =(const float*)d_in[53];
    const float* W9a =(const float*)d_in[54]; const float* b9a =(const float*)d_in[55];
    const float* W9b =(const float*)d_in[56]; const float* b9b =(const float*)d_in[57];
    const float* Wf  =(const float*)d_in[58]; const float* bfb =(const float*)d_in[59];

    float* ws = (float*)d_ws;
    auto pad4 = [](size_t x) { return (x + 3) & ~(size_t)3; };
    auto nbinsOf = [](int nd) { return (nd + 1023) >> 10; };

    const int sI_in[2]  = {2, 4};
    const int sI_nd[2]  = {NFc, N0c};
    const int sII_in[14] = {6, 8, 10, 12, 14, 16, 18, 20, 22, 24, 26, 28, 30, 32};
    const int sII_nd[14] = {NCc, N0c, N1c, N2c, N3c, N4c, N1c, N2c, N3c, N4c,
                            N0c, N1c, N2c, N3c};

    // ---- zone sizing (4B units); node ranges padded to 1024 per set ----
    size_t sumNdPadI = 0, sumEI = 0, sumNdPadII = 0, sumEII = 0;
    for (int t = 0; t < 2;  ++t) { sumNdPadI  += (size_t)nbinsOf(sI_nd[t])  << 10; sumEI  += EN(sI_in[t]); }
    for (int t = 0; t < 14; ++t) { sumNdPadII += (size_t)nbinsOf(sII_nd[t]) << 10; sumEII += EN(sII_in[t]); }
    size_t zI  = pad4(sumNdPadI  + 1) + pad4(2 * sumEI);
    size_t zII = pad4(sumNdPadII + 1) + pad4(2 * sumEII);
    size_t zAB = (zI > zII) ? zI : zII;
    size_t zD_o   = zAB;
    size_t part_o = zD_o + ZDCAP;
    size_t zC_o   = part_o + 1024;
    size_t t_o    = zI;          // fp pre-transform scratch (Stage I only)

    int* part = (int*)(ws + part_o);
    const int B = 256;
    auto G = [&](int n) { return dim3((unsigned)((n + B - 1) / B)); };

    // Fused multi-set bucketed build: per group {mhist, scan1/2/3, mscat,
    // mcsr} = 6 launches.
    auto buildStage = [&](int ns, const int* sin, const int* snd,
                          int* starts, int2* pool, int* doffOut) {
        int nbinsA[14], nblkA[14];
        long long eoffA[14];
        long long sumNdPad = 0, sumE = 0;
        for (int t = 0; t < ns; ++t) {
            int nd = snd[t], E = EN(sin[t]);
            doffOut[t] = (int)sumNdPad;
            nbinsA[t] = (nd + 1023) >> 10;
            sumNdPad += (long long)nbinsA[t] << 10;
            nblkA[t] = (E + CH - 1) / CH;
            eoffA[t] = sumE;
            sumE += E;
        }
        int t0 = 0;
        while (t0 < ns) {
            long long cost = 0; int t1 = t0;
            while (t1 < ns) {
                long long c = 2LL * EN(sin[t1]) + (long long)nbinsA[t1] * nblkA[t1];
                if (t1 > t0 && cost + c + 1 > (long long)ZDCAP) break;
                cost += c; ++t1;
            }
            BuildTab tb{};
            int gn = t1 - t0, tc = 0, tbn = 0, maxNb = 0;
            long long LA = 0, gE = 0;
            for (int t = t0; t < t1; ++t) {
                int q = t - t0;
                tb.src[q] = SRC(sin[t]); tb.dst[q] = DST(sin[t]); tb.ea[q] = EA(sin[t]);
                tb.chunkBase[q] = tc; tb.binBase[q] = tbn;
                tb.moff[q] = (int)LA; tb.doff[q] = doffOut[t];
                tb.E[q] = EN(sin[t]); tb.nblk[q] = nblkA[t]; tb.nbins[q] = nbinsA[t];
                tc += nblkA[t]; tbn += nbinsA[t];
                LA += (long long)nbinsA[t] * nblkA[t]; gE += EN(sin[t]);
                if (nbinsA[t] > maxNb) maxNb = nbinsA[t];
            }
            tb.chunkBase[gn] = tc; tb.binBase[gn] = tbn; tb.nsets = gn;
            int2* brec = (int2*)(ws + zD_o);
            int*  hist = (int*)(ws + zD_o) + 2 * gE;
            if (maxNb > 1024)
                mhist_k<2048><<<dim3((unsigned)tc), 1024, 0, stream>>>(tb, hist);
            else
                mhist_k<1024><<<dim3((unsigned)tc), 1024, 0, stream>>>(tb, hist);
            int nb = (int)((LA + SCHUNK - 1) / SCHUNK);
            scan1_k<<<dim3((unsigned)nb), B, 0, stream>>>(hist, hist, part, (int)LA);
            scan2_k<<<dim3(1), 1024, 0, stream>>>(part, nb);
            scan3_k<<<G((int)LA + 1), B, 0, stream>>>(hist, part, (int)LA, (int)gE);
            if (maxNb > 1024)
                mscat_k<2048><<<dim3((unsigned)tc), 1024, 0, stream>>>(tb, hist, brec);
            else
                mscat_k<1024><<<dim3((unsigned)tc), 1024, 0, stream>>>(tb, hist, brec);
            long long gBase = eoffA[t0];
            mcsr_k<<<dim3((unsigned)tbn), 1024, 0, stream>>>(
                tb, brec, hist, starts, pool + gBase, (int)gBase);
            t0 = t1;
        }
    };

    // ---- feature buffers ----
    float* t   = ws + t_o;                   // [NF,16] fp pre-transform, 1-2
    float* c1  = ws + zC_o;                  // [N0,16], steps 2-18 (tail zone)
    float* tpc = c1;                         // steps 19.5-21 (c1 dead)
    size_t mb = zD_o;
    auto mal = [&](size_t n) { size_t o = mb; mb += pad4(n); return ws + o; };
    float* p1  = mal((size_t)N1c*16);
    float* c2  = mal((size_t)N1c*16);
    float* p2  = mal((size_t)N2c*16);
    float* c3  = mal((size_t)N2c*16);
    float* p3  = mal((size_t)N3c*16);
    float* c4  = mal((size_t)N3c*32);
    float* p4  = mal((size_t)N4c*32);
    float* c5a = mal((size_t)N4c*32);
    float* c5b = mal((size_t)N4c*32);
    float* t6  = mal((size_t)N3c*32);
    float* g6  = mal((size_t)N3c*32);
    float* t7  = mal((size_t)N2c*32);
    float* g7  = mal((size_t)N2c*32);
    float* t8  = mal((size_t)N1c*16);
    float* g8  = mal((size_t)N1c*16);        // arena ends ~zD_o+12.06M <= ZDCAP
    // t9 OVERLAYS zD_o[0,8M): at step 18 all mids below g8's 10.06M offset
    // are dead (p1..t8); g8 [10.06M,12.06M) and c1 (tail zone) are disjoint.
    float* t9  = ws + zD_o;
    float* out = (float*)d_out;

    // ---- Stage I: cf+fp CSRs (one group) + steps 1-2 ----
    int* startsI = (int*)(ws + 0);
    int2* poolI  = (int2*)(ws + pad4(sumNdPadI + 1));
    int doffI[2];
    buildStage(2, sI_in, sI_nd, startsI, poolI, doffI);
    // 1) fused: h = relu(gather(cf,xc)@W_cf+b_cf); t = [h||xf]@W_fp  [NF,16]
    cffp_k<<<G(NFc), B, 0, stream>>>(
        xc, xf, poolI, startsI + doffI[0], W_cf, b_cf, W_fp, t, NFc);
    // 2) c1 = relu(gather(fp, t) + b_fp)                       [N0,16]
    gather_sw_k<16,true><<<G(N0c), B, 0, stream>>>(
        t, poolI, startsI + doffI[1], b_fp, c1, N0c);

    // ---- Stage II: 14 remaining CSRs (2 groups; t dead) ----
    int* startsII = (int*)(ws + 0);
    int2* poolII  = (int2*)(ws + pad4(sumNdPadII + 1));
    int doffII[14];
    buildStage(14, sII_in, sII_nd, startsII, poolII, doffII);
    enum { f_pc, f_pp0, f_pp1, f_pp2, f_pp3, f_pp4, f_po0, f_po1, f_po2, f_po3,
           f_up0, f_up1, f_up2, f_up3 };
    auto st = [&](int t_) { return startsII + doffII[t_]; };
    int2* ec = poolII;

    // ---- Stage III: pipeline ----
    // 3) p1 = gather(pool0, c1)
    gather_sw_k<16,false><<<G(N1c), B, 0, stream>>>(c1, ec, st(f_po0), nullptr, p1, N1c);
    // 4) c2
    gather_conv_k<16,0,16><<<G(N1c), B, 0, stream>>>(p1, nullptr, ec, st(f_pp1), W2, b2, c2, N1c);
    // 5) p2
    gather_sw_k<16,false><<<G(N2c), B, 0, stream>>>(c2, ec, st(f_po1), nullptr, p2, N2c);
    // 6) c3
    gather_conv_k<16,0,16><<<G(N2c), B, 0, stream>>>(p2, nullptr, ec, st(f_pp2), W3, b3, c3, N2c);
    // 7) p3
    gather_sw_k<16,false><<<G(N3c), B, 0, stream>>>(c3, ec, st(f_po2), nullptr, p3, N3c);
    // 8) c4
    gather_conv_k<16,0,32><<<G(N3c), B, 0, stream>>>(p3, nullptr, ec, st(f_pp3), W4, b4, c4, N3c);
    // 9) p4
    gather_sw_k<32,false><<<G(N4c), B, 0, stream>>>(c4, ec, st(f_po3), nullptr, p4, N4c);
    // 10) c5a
    gather_conv_k<32,0,32><<<G(N4c), B, 0, stream>>>(p4, nullptr, ec, st(f_pp4), W5a, b5a, c5a, N4c);
    // 11) c5b
    gather_conv_k<32,0,32><<<G(N4c), B, 0, stream>>>(c5a, nullptr, ec, st(f_pp4), W5b, b5b, c5b, N4c);
    // 12+13a) t6 = [gather(unpool3, c5b) || c4] @ W6
    gather_dense_k<32,32,32,false><<<G(N3c), B, 0, stream>>>(
        c5b, c4, ec, st(f_up3), nullptr, W6, t6, N3c);
    // 13b) g6 = relu(gather(pp3, t6) + b6)
    gather_sw_k<32,true><<<G(N3c), B, 0, stream>>>(t6, ec, st(f_pp3), b6, g6, N3c);
    // 14+15a) t7 = [gather(unpool2, g6) || c3] @ W7
    gather_dense_k<32,16,32,false><<<G(N2c), B, 0, stream>>>(
        g6, c3, ec, st(f_up2), nullptr, W7, t7, N2c);
    // 15b) g7
    gather_sw_k<32,true><<<G(N2c), B, 0, stream>>>(t7, ec, st(f_pp2), b7, g7, N2c);
    // 16+17a) t8 = [gather(unpool1, g7) || c2] @ W8
    gather_dense_k<32,16,16,false><<<G(N1c), B, 0, stream>>>(
        g7, c2, ec, st(f_up1), nullptr, W8, t8, N1c);
    // 17b) g8
    gather_sw_k<16,true><<<G(N1c), B, 0, stream>>>(t8, ec, st(f_pp1), b8, g8, N1c);
    // 18+19a) t9 = [gather(unpool0, g8) || c1] @ W9a   (t9 overlays dead mids)
    gather_dense_k<16,16,16,false><<<G(N0c), B, 0, stream>>>(
        g8, c1, ec, st(f_up0), nullptr, W9a, t9, N0c);
    // 19b+20) tpc = relu(gather(pp0, t9) + b9a) @ W9b   (overlays c1)
    gather_dense_k<16,0,16,true><<<G(N0c), B, 0, stream>>>(
        t9, nullptr, ec, st(f_pp0), b9a, W9b, tpc, N0c);
    // 21) fused pc gather + bias + relu + Wf dot
    gather_final_k<<<G(NCc), B, 0, stream>>>(tpc, ec, st(f_pc), b9b, Wf, bfb, out, NCc);
}

// Round 7
// 1362.381 us; speedup vs baseline: 1.7825x; 1.1103x over previous
//
#include <hip/hip_runtime.h>
#include <cstdint>
#include <cstddef>

// ---------------------------------------------------------------------------
// GraphUNetSmall, round 12: coalesce mscat's scattered record writes.
//
// R11 post-mortem: mscat occupancy 19->59% but dur only 164->150us; HBM 20%,
// VALU 2.8% -> bound by WRITE TRANSACTIONS (57.7G/s ~ 3/cy/XCD): each wave
// stores 64x8B to 64 different bucket runs. Fix: LDS bucket-sort staging.
// Per 8K-edge half: LDS-rank -> LDS scan -> scatter records into LDS in
// bucket order (srec+sbkt) -> position-ordered drain so consecutive lanes
// write consecutive addresses within each run (~10 transactions/wave vs 64).
// LDS 116KB -> 1 block/CU (16 waves, 50% occ) — fine for streaming.
// Records byte-identical; only within-node insertion order shifts.
// ---------------------------------------------------------------------------

#define DEV __device__ __forceinline__

static constexpr int NCc = 1000000;
static constexpr int NFc = 1500000;
static constexpr int N0c = 500000;
static constexpr int N1c = 125000;
static constexpr int N2c = 31250;
static constexpr int N3c = 7813;
static constexpr int N4c = 1954;
static constexpr int SCHUNK = 8192;   // elems per scan block (256 thr * 32)
static constexpr int CH = 16384;      // edges per bucket-build block
static constexpr int HALF = 8192;     // mscat sub-chunk staged in LDS
static constexpr size_t ZDCAP = 17690000;  // ZoneD capacity, 4B units

// Per-group set table for the fused build kernels (kernarg, <=4KB).
struct BuildTab {
    const int*   src[14];
    const int*   dst[14];
    const float* ea[14];
    int chunkBase[15];   // prefix of nblk
    int binBase[15];     // prefix of nbins
    int moff[14];        // matrix offset = prefix of nbins*nblk
    int doff[14];        // absolute starts-array offset of set
    int E[14];
    int nblk[14];
    int nbins[14];
    int nsets;
};

// ---------------- bucketed CSR build (zero global atomics) ----------------

// Phase 1a: per-block LDS histogram over 1024-node buckets, multi-set.
template<int NB>
__global__ void __launch_bounds__(1024)
mhist_k(BuildTab tab, int* __restrict__ histG)
{
    __shared__ int sh[NB];
    int j = blockIdx.x, t = 0;
    while (j >= tab.chunkBase[t + 1]) ++t;
    int lj = j - tab.chunkBase[t];
    int nbins = tab.nbins[t], nblk = tab.nblk[t], E = tab.E[t];
    const int* __restrict__ dst = tab.dst[t];
    int* hg = histG + tab.moff[t];
    int tx = threadIdx.x;
    for (int i = tx; i < nbins; i += 1024) sh[i] = 0;
    __syncthreads();
    int base = j == j ? lj * CH + tx : 0;
    for (int k0 = 0; k0 < 16; k0 += 8) {
        int d8[8];
#pragma unroll
        for (int k = 0; k < 8; ++k) {
            int e = base + (k0 + k) * 1024;
            d8[k] = (e < E) ? dst[e] : -1;
        }
#pragma unroll
        for (int k = 0; k < 8; ++k)
            if (d8[k] >= 0) atomicAdd(&sh[d8[k] >> 10], 1);
    }
    __syncthreads();
    for (int i = tx; i < nbins; i += 1024) hg[i * nblk + lj] = sh[i];
}

// Phase 1b: LDS bucket-sort staging + coalesced drain.
// Per HALF: rank via hcnt atomics -> scan -> scatter to LDS bucket-ordered
// (srec/sbkt) -> drain position-ordered (consecutive lanes -> consecutive
// global addresses within each (bucket,block) run). cum[] carries per-bucket
// counts across halves. Records: (dlow<<21|src, ea_bits), src < 2^21.
template<int NB>
__global__ void __launch_bounds__(1024)
mscat_k(BuildTab tab, const int* __restrict__ scanS, int2* __restrict__ brec)
{
    __shared__ int hcnt[NB];
    __shared__ int bas[NB];
    __shared__ int cum[NB];
    __shared__ int lstart[NB];
    __shared__ int sd[1024];
    __shared__ int2 srec[HALF];
    __shared__ unsigned short sbkt[HALF];
    int j = blockIdx.x, t = 0;
    while (j >= tab.chunkBase[t + 1]) ++t;
    int lj = j - tab.chunkBase[t];
    int nbins = tab.nbins[t], nblk = tab.nblk[t], E = tab.E[t];
    const int* __restrict__ src = tab.src[t];
    const int* __restrict__ dst = tab.dst[t];
    const float* __restrict__ ea = tab.ea[t];
    const int* sc = scanS + tab.moff[t];
    int tx = threadIdx.x;
    for (int i = tx; i < NB; i += 1024) cum[i] = 0;
    for (int i = tx; i < nbins; i += 1024) bas[i] = sc[i * nblk + lj];
    __syncthreads();

    for (int h = 0; h < CH / HALF; ++h) {
        // zero per-half hist
        for (int i = tx; i < NB; i += 1024) hcnt[i] = 0;
        __syncthreads();
        // pass 1: load 8 edges, rank via LDS atomics; keep in registers
        int bl8[8], r8[8]; int2 rec8[8];
        int base = lj * CH + h * HALF + tx;
#pragma unroll
        for (int k = 0; k < 8; ++k) {
            int e = base + k * 1024;
            if (e < E) {
                int d = dst[e];
                bl8[k] = d >> 10;
                rec8[k] = make_int2(((d & 1023) << 21) | src[e],
                                    __float_as_int(ea[e]));
                r8[k] = atomicAdd(&hcnt[bl8[k]], 1);
            } else bl8[k] = -1;
        }
        __syncthreads();
        // exclusive scan of hcnt -> lstart
        if constexpr (NB == 1024) {
            int v = hcnt[tx];
            sd[tx] = v; __syncthreads();
            for (int off = 1; off < 1024; off <<= 1) {
                int y = (tx >= off) ? sd[tx - off] : 0;
                __syncthreads();
                sd[tx] += y;
                __syncthreads();
            }
            lstart[tx] = sd[tx] - v;
        } else {
            int v0 = hcnt[tx * 2], v1 = hcnt[tx * 2 + 1];
            int s = v0 + v1;
            sd[tx] = s; __syncthreads();
            for (int off = 1; off < 1024; off <<= 1) {
                int y = (tx >= off) ? sd[tx - off] : 0;
                __syncthreads();
                sd[tx] += y;
                __syncthreads();
            }
            int run = sd[tx] - s;
            lstart[tx * 2] = run; lstart[tx * 2 + 1] = run + v0;
        }
        __syncthreads();
        int tot = lstart[NB - 1] + hcnt[NB - 1];
        // scatter into LDS in bucket order
#pragma unroll
        for (int k = 0; k < 8; ++k) {
            if (bl8[k] >= 0) {
                int pos = lstart[bl8[k]] + r8[k];
                srec[pos] = rec8[k];
                sbkt[pos] = (unsigned short)bl8[k];
            }
        }
        __syncthreads();
        // drain: position-ordered, coalesced within runs
        for (int pos = tx; pos < tot; pos += 1024) {
            int b = sbkt[pos];
            brec[bas[b] + cum[b] + (pos - lstart[b])] = srec[pos];
        }
        __syncthreads();
        // carry counts to next half
        for (int i = tx; i < NB; i += 1024) cum[i] += hcnt[i];
        __syncthreads();
    }
}

// Phase 2: one block per bucket, multi-set, 1024 threads (one bin each).
__global__ void __launch_bounds__(1024)
mcsr_k(BuildTab tab, const int2* __restrict__ brec, const int* __restrict__ scanS,
       int* __restrict__ starts, int2* __restrict__ poolG, int sbias)
{
    __shared__ int cnt[1024];
    __shared__ int lst[1024];
    __shared__ int sd[1024];
    int b = blockIdx.x, t = 0;
    while (b >= tab.binBase[t + 1]) ++t;
    int bl = b - tab.binBase[t];
    int nblk = tab.nblk[t];
    int mo = tab.moff[t];
    int tx = threadIdx.x;
    int bs = scanS[mo + bl * nblk];
    int be = scanS[mo + (bl + 1) * nblk];
    cnt[tx] = 0;
    __syncthreads();
    // pass A: per-node counts (4-deep)
    int i = bs + tx;
    for (; i + 3072 < be; i += 4096) {
        int2 r0 = brec[i], r1 = brec[i + 1024], r2 = brec[i + 2048], r3 = brec[i + 3072];
        atomicAdd(&cnt[(unsigned)r0.x >> 21], 1);
        atomicAdd(&cnt[(unsigned)r1.x >> 21], 1);
        atomicAdd(&cnt[(unsigned)r2.x >> 21], 1);
        atomicAdd(&cnt[(unsigned)r3.x >> 21], 1);
    }
    for (; i < be; i += 1024) atomicAdd(&cnt[(unsigned)brec[i].x >> 21], 1);
    __syncthreads();
    // exclusive scan, one bin per thread
    int v = cnt[tx];
    sd[tx] = v; __syncthreads();
    for (int off = 1; off < 1024; off <<= 1) {
        int y = (tx >= off) ? sd[tx - off] : 0;
        __syncthreads();
        sd[tx] += y;
        __syncthreads();
    }
    lst[tx] = sd[tx] - v;
    __syncthreads();
    int* startsSet = starts + tab.doff[t];
    int gb = sbias + bs;
    startsSet[(bl << 10) + tx] = gb + lst[tx];
    cnt[tx] = 0;
    __syncthreads();
    // pass B: scatter into final CSR pool (cursor = zeroed cnt)
    i = bs + tx;
    for (; i < be; i += 1024) {
        int2 rec = brec[i];
        int dl = (unsigned)rec.x >> 21;
        int r = atomicAdd(&cnt[dl], 1);
        poolG[bs + lst[dl] + r] = make_int2(rec.x & 0x1FFFFF, rec.y);
    }
}

// ---------------- scans (alias-safe for in-place use) ----------
__global__ void __launch_bounds__(256)
scan1_k(const int* deg, int* starts, int* part, int n)
{
    __shared__ int sd[256];
    int t = threadIdx.x;
    int base = blockIdx.x * SCHUNK + t * 32;
    int v[32]; int sum = 0;
#pragma unroll
    for (int k = 0; k < 32; ++k) { int i = base + k; v[k] = (i < n) ? deg[i] : 0; sum += v[k]; }
    sd[t] = sum; __syncthreads();
    for (int off = 1; off < 256; off <<= 1) {
        int y = (t >= off) ? sd[t - off] : 0;
        __syncthreads();
        sd[t] += y;
        __syncthreads();
    }
    int run = sd[t] - sum;
#pragma unroll
    for (int k = 0; k < 32; ++k) { int i = base + k; if (i < n) starts[i] = run; run += v[k]; }
    if (t == 255) part[blockIdx.x] = sd[255];
}

__global__ void __launch_bounds__(1024)
scan2_k(int* __restrict__ part, int nb)
{
    __shared__ int sd[1024];
    int t = threadIdx.x;
    int v = (t < nb) ? part[t] : 0;
    sd[t] = v; __syncthreads();
    for (int off = 1; off < 1024; off <<= 1) {
        int y = (t >= off) ? sd[t - off] : 0;
        __syncthreads();
        sd[t] += y;
        __syncthreads();
    }
    if (t < nb) part[t] = sd[t] - v;
}

__global__ void __launch_bounds__(256)
scan3_k(int* __restrict__ starts, const int* __restrict__ part, int n, int Etot)
{
    int i = blockIdx.x * 256 + threadIdx.x;
    if (i < n) starts[i] += part[i / SCHUNK];
    if (i == 0) starts[n] = Etot;
}

// ---------------- compute ----------------
template<int F>
DEV void row_fma(const float* __restrict__ p, float w, float* acc)
{
    static_assert(F % 4 == 0, "");
#pragma unroll
    for (int k = 0; k < F; k += 4) {
        float4 v = *reinterpret_cast<const float4*>(p + k);
        acc[k+0] = fmaf(w, v.x, acc[k+0]); acc[k+1] = fmaf(w, v.y, acc[k+1]);
        acc[k+2] = fmaf(w, v.z, acc[k+2]); acc[k+3] = fmaf(w, v.w, acc[k+3]);
    }
}

// Fused step 1+1.5: per face, gather cf (xc 8B rows), W_cf+b_cf+relu in regs,
// then t = [h12||xf] @ W_fp -> one aligned 64B row.
__global__ void __launch_bounds__(256)
cffp_k(const float* __restrict__ xc, const float* __restrict__ xf,
       const int2* __restrict__ ecsr, const int* __restrict__ starts,
       const float* __restrict__ W_cf, const float* __restrict__ b_cf,
       const float* __restrict__ W_fp, float* __restrict__ t, int n)
{
    __shared__ float sWcf[24];
    __shared__ float sbcf[12];
    __shared__ float sWfp[256];
    for (int i = threadIdx.x; i < 24;  i += 256) sWcf[i] = W_cf[i];
    for (int i = threadIdx.x; i < 12;  i += 256) sbcf[i] = b_cf[i];
    for (int i = threadIdx.x; i < 256; i += 256) sWfp[i] = W_fp[i];
    __syncthreads();
    int d = blockIdx.x * 256 + threadIdx.x;
    if (d >= n) return;
    int i0 = starts[d], i1 = starts[d + 1];
    float a0 = 0.f, a1 = 0.f;
    for (int i = i0; i < i1; ++i) {
        int2 rec = ecsr[i];
        float2 v = *reinterpret_cast<const float2*>(xc + (size_t)rec.x * 2);
        float w = __int_as_float(rec.y);
        a0 = fmaf(w, v.x, a0); a1 = fmaf(w, v.y, a1);
    }
    float h12[12];
#pragma unroll
    for (int j = 0; j < 12; ++j)
        h12[j] = fmaxf(fmaf(a0, sWcf[j], fmaf(a1, sWcf[12 + j], sbcf[j])), 0.f);
    float4 xfv = *reinterpret_cast<const float4*>(xf + (size_t)d * 4);
    float* op = t + (size_t)d * 16;
#pragma unroll
    for (int o = 0; o < 16; o += 4) {
        float4 y; float* yp = &y.x;
#pragma unroll
        for (int jj = 0; jj < 4; ++jj) {
            int oo = o + jj;
            float s =      xfv.x * sWfp[12 * 16 + oo];
            s = fmaf(xfv.y, sWfp[13 * 16 + oo], s);
            s = fmaf(xfv.z, sWfp[14 * 16 + oo], s);
            s = fmaf(xfv.w, sWfp[15 * 16 + oo], s);
#pragma unroll
            for (int j = 0; j < 12; ++j) s = fmaf(h12[j], sWfp[j * 16 + oo], s);
            yp[jj] = s;
        }
        *reinterpret_cast<float4*>(op + o) = y;
    }
}

template<int F, bool EPI>
__global__ void __launch_bounds__(256)
gather_sw_k(const float* __restrict__ x, const int2* __restrict__ ecsr,
            const int* __restrict__ starts, const float* __restrict__ b,
            float* __restrict__ out, int n)
{
    int d = blockIdx.x * 256 + threadIdx.x;
    if (d >= n) return;
    int i0 = starts[d], i1 = starts[d + 1];
    float acc[F];
#pragma unroll
    for (int k = 0; k < F; ++k) acc[k] = 0.f;
    for (int i = i0; i < i1; ++i) {
        int2 rec = ecsr[i];
        row_fma<F>(x + (size_t)rec.x * F, __int_as_float(rec.y), acc);
    }
    if constexpr (EPI) {
#pragma unroll
        for (int k = 0; k < F; ++k) acc[k] = fmaxf(acc[k] + b[k], 0.f);
    }
    float* op = out + (size_t)d * F;
#pragma unroll
    for (int k = 0; k < F; k += 4)
        *reinterpret_cast<float4*>(op + k) = make_float4(acc[k], acc[k+1], acc[k+2], acc[k+3]);
}

template<int FI1, int FI2, int FO>
__global__ void __launch_bounds__(256)
gather_conv_k(const float* __restrict__ x1, const float* __restrict__ x2,
              const int2* __restrict__ ecsr, const int* __restrict__ starts,
              const float* __restrict__ W, const float* __restrict__ b,
              float* __restrict__ out, int n)
{
    constexpr int FI = FI1 + FI2;
    __shared__ float sW[FI * FO];
    for (int i = threadIdx.x; i < FI * FO; i += 256) sW[i] = W[i];
    __syncthreads();
    int d = blockIdx.x * 256 + threadIdx.x;
    if (d >= n) return;
    int i0 = starts[d], i1 = starts[d + 1];
    float acc[FI];
#pragma unroll
    for (int k = 0; k < FI; ++k) acc[k] = 0.f;
    for (int i = i0; i < i1; ++i) {
        int2 rec = ecsr[i];
        float w = __int_as_float(rec.y);
        row_fma<FI1>(x1 + (size_t)rec.x * FI1, w, acc);
        if constexpr (FI2 > 0)
            row_fma<FI2>(x2 + (size_t)rec.x * FI2, w, acc + FI1);
    }
    float* op = out + (size_t)d * FO;
#pragma unroll
    for (int fo = 0; fo < FO; fo += 4) {
        float4 y; float* yp = &y.x;
#pragma unroll
        for (int j = 0; j < 4; ++j) {
            float s = b[fo + j];
#pragma unroll
            for (int k = 0; k < FI; ++k) s = fmaf(acc[k], sW[k * FO + fo + j], s);
            yp[j] = fmaxf(s, 0.f);
        }
        *reinterpret_cast<float4*>(op + fo) = y;
    }
}

// Fused gather + dense: acc = gather(F1) [optionally relu(acc+bpre)];
// out = [acc || x2[d]] @ W (no epilogue bias/relu — applied downstream).
template<int F1, int F2, int FO, bool EPIB>
__global__ void __launch_bounds__(256)
gather_dense_k(const float* __restrict__ x, const float* __restrict__ x2,
               const int2* __restrict__ ecsr, const int* __restrict__ starts,
               const float* __restrict__ bpre, const float* __restrict__ W,
               float* __restrict__ out, int n)
{
    constexpr int FI = F1 + F2;
    __shared__ float sW[FI * FO];
    for (int i = threadIdx.x; i < FI * FO; i += 256) sW[i] = W[i];
    __syncthreads();
    int d = blockIdx.x * 256 + threadIdx.x;
    if (d >= n) return;
    int i0 = starts[d], i1 = starts[d + 1];
    float acc[F1];
#pragma unroll
    for (int k = 0; k < F1; ++k) acc[k] = 0.f;
    for (int i = i0; i < i1; ++i) {
        int2 rec = ecsr[i];
        row_fma<F1>(x + (size_t)rec.x * F1, __int_as_float(rec.y), acc);
    }
    if constexpr (EPIB) {
#pragma unroll
        for (int k = 0; k < F1; ++k) acc[k] = fmaxf(acc[k] + bpre[k], 0.f);
    }
    float xin2[F2 > 0 ? F2 : 1];
    if constexpr (F2 > 0) {
        const float* p = x2 + (size_t)d * F2;
#pragma unroll
        for (int k = 0; k < F2; k += 4) {
            float4 v = *reinterpret_cast<const float4*>(p + k);
            xin2[k] = v.x; xin2[k+1] = v.y; xin2[k+2] = v.z; xin2[k+3] = v.w;
        }
    }
    float* op = out + (size_t)d * FO;
#pragma unroll
    for (int fo = 0; fo < FO; fo += 4) {
        float4 y; float* yp = &y.x;
#pragma unroll
        for (int j = 0; j < 4; ++j) {
            float s = 0.f;
#pragma unroll
            for (int k = 0; k < F1; ++k) s = fmaf(acc[k], sW[k * FO + fo + j], s);
            if constexpr (F2 > 0)
#pragma unroll
                for (int k = 0; k < F2; ++k) s = fmaf(xin2[k], sW[(F1 + k) * FO + fo + j], s);
            yp[j] = s;
        }
        *reinterpret_cast<float4*>(op + fo) = y;
    }
}

__global__ void __launch_bounds__(256)
gather_final_k(const float* __restrict__ x, const int2* __restrict__ ecsr,
               const int* __restrict__ starts, const float* __restrict__ b9b,
               const float* __restrict__ Wf, const float* __restrict__ bf,
               float* __restrict__ out, int n)
{
    int d = blockIdx.x * 256 + threadIdx.x;
    if (d >= n) return;
    int i0 = starts[d], i1 = starts[d + 1];
    float acc[16];
#pragma unroll
    for (int k = 0; k < 16; ++k) acc[k] = 0.f;
    for (int i = i0; i < i1; ++i) {
        int2 rec = ecsr[i];
        row_fma<16>(x + (size_t)rec.x * 16, __int_as_float(rec.y), acc);
    }
    float y = bf[0];
#pragma unroll
    for (int k = 0; k < 16; ++k) y = fmaf(fmaxf(acc[k] + b9b[k], 0.f), Wf[k], y);
    out[d] = y;
}

// ---------------- host ----------------
extern "C" void kernel_launch(void* const* d_in, const int* in_sizes, int n_in,
                              void* d_out, int out_size, void* d_ws, size_t ws_size,
                              hipStream_t stream)
{
    const float* xc = (const float*)d_in[0];
    const float* xf = (const float*)d_in[1];

    auto SRC = [&](int i) { return (const int*)d_in[i]; };
    auto DST = [&](int i) { return (const int*)d_in[i] + in_sizes[i] / 2; };
    auto EA  = [&](int i) { return (const float*)d_in[i + 1]; };
    auto EN  = [&](int i) { return in_sizes[i] / 2; };

    const float* W_cf=(const float*)d_in[34]; const float* b_cf=(const float*)d_in[35];
    const float* W_fp=(const float*)d_in[36]; const float* b_fp=(const float*)d_in[37];
    const float* W2  =(const float*)d_in[38]; const float* b2  =(const float*)d_in[39];
    const float* W3  =(const float*)d_in[40]; const float* b3  =(const float*)d_in[41];
    const float* W4  =(const float*)d_in[42]; const float* b4  =(const float*)d_in[43];
    const float* W5a =(const float*)d_in[44]; const float* b5a =(const float*)d_in[45];
    const float* W5b =(const float*)d_in[46]; const float* b5b =(const float*)d_in[47];
    const float* W6  =(const float*)d_in[48]; const float* b6  =(const float*)d_in[49];
    const float* W7  =(const float*)d_in[50]; const float* b7  =(const float*)d_in[51];
    const float* W8  =(const float*)d_in[52]; const float* b8  =(const float*)d_in[53];
    const float* W9a =(const float*)d_in[54]; const float* b9a =(const float*)d_in[55];
    const float* W9b =(const float*)d_in[56]; const float* b9b =(const float*)d_in[57];
    const float* Wf  =(const float*)d_in[58]; const float* bfb =(const float*)d_in[59];

    float* ws = (float*)d_ws;
    auto pad4 = [](size_t x) { return (x + 3) & ~(size_t)3; };
    auto nbinsOf = [](int nd) { return (nd + 1023) >> 10; };

    const int sI_in[2]  = {2, 4};
    const int sI_nd[2]  = {NFc, N0c};
    const int sII_in[14] = {6, 8, 10, 12, 14, 16, 18, 20, 22, 24, 26, 28, 30, 32};
    const int sII_nd[14] = {NCc, N0c, N1c, N2c, N3c, N4c, N1c, N2c, N3c, N4c,
                            N0c, N1c, N2c, N3c};

    // ---- zone sizing (4B units); node ranges padded to 1024 per set ----
    size_t sumNdPadI = 0, sumEI = 0, sumNdPadII = 0, sumEII = 0;
    for (int t = 0; t < 2;  ++t) { sumNdPadI  += (size_t)nbinsOf(sI_nd[t])  << 10; sumEI  += EN(sI_in[t]); }
    for (int t = 0; t < 14; ++t) { sumNdPadII += (size_t)nbinsOf(sII_nd[t]) << 10; sumEII += EN(sII_in[t]); }
    size_t zI  = pad4(sumNdPadI  + 1) + pad4(2 * sumEI);
    size_t zII = pad4(sumNdPadII + 1) + pad4(2 * sumEII);
    size_t zAB = (zI > zII) ? zI : zII;
    size_t zD_o   = zAB;
    size_t part_o = zD_o + ZDCAP;
    size_t zC_o   = part_o + 1024;
    size_t t_o    = zI;          // fp pre-transform scratch (Stage I only)

    int* part = (int*)(ws + part_o);
    const int B = 256;
    auto G = [&](int n) { return dim3((unsigned)((n + B - 1) / B)); };

    // Fused multi-set bucketed build: per group {mhist, scan1/2/3, mscat,
    // mcsr} = 6 launches.
    auto buildStage = [&](int ns, const int* sin, const int* snd,
                          int* starts, int2* pool, int* doffOut) {
        int nbinsA[14], nblkA[14];
        long long eoffA[14];
        long long sumNdPad = 0, sumE = 0;
        for (int t = 0; t < ns; ++t) {
            int nd = snd[t], E = EN(sin[t]);
            doffOut[t] = (int)sumNdPad;
            nbinsA[t] = (nd + 1023) >> 10;
            sumNdPad += (long long)nbinsA[t] << 10;
            nblkA[t] = (E + CH - 1) / CH;
            eoffA[t] = sumE;
            sumE += E;
        }
        int t0 = 0;
        while (t0 < ns) {
            long long cost = 0; int t1 = t0;
            while (t1 < ns) {
                long long c = 2LL * EN(sin[t1]) + (long long)nbinsA[t1] * nblkA[t1];
                if (t1 > t0 && cost + c + 1 > (long long)ZDCAP) break;
                cost += c; ++t1;
            }
            BuildTab tb{};
            int gn = t1 - t0, tc = 0, tbn = 0, maxNb = 0;
            long long LA = 0, gE = 0;
            for (int t = t0; t < t1; ++t) {
                int q = t - t0;
                tb.src[q] = SRC(sin[t]); tb.dst[q] = DST(sin[t]); tb.ea[q] = EA(sin[t]);
                tb.chunkBase[q] = tc; tb.binBase[q] = tbn;
                tb.moff[q] = (int)LA; tb.doff[q] = doffOut[t];
                tb.E[q] = EN(sin[t]); tb.nblk[q] = nblkA[t]; tb.nbins[q] = nbinsA[t];
                tc += nblkA[t]; tbn += nbinsA[t];
                LA += (long long)nbinsA[t] * nblkA[t]; gE += EN(sin[t]);
                if (nbinsA[t] > maxNb) maxNb = nbinsA[t];
            }
            tb.chunkBase[gn] = tc; tb.binBase[gn] = tbn; tb.nsets = gn;
            int2* brec = (int2*)(ws + zD_o);
            int*  hist = (int*)(ws + zD_o) + 2 * gE;
            if (maxNb > 1024)
                mhist_k<2048><<<dim3((unsigned)tc), 1024, 0, stream>>>(tb, hist);
            else
                mhist_k<1024><<<dim3((unsigned)tc), 1024, 0, stream>>>(tb, hist);
            int nb = (int)((LA + SCHUNK - 1) / SCHUNK);
            scan1_k<<<dim3((unsigned)nb), B, 0, stream>>>(hist, hist, part, (int)LA);
            scan2_k<<<dim3(1), 1024, 0, stream>>>(part, nb);
            scan3_k<<<G((int)LA + 1), B, 0, stream>>>(hist, part, (int)LA, (int)gE);
            if (maxNb > 1024)
                mscat_k<2048><<<dim3((unsigned)tc), 1024, 0, stream>>>(tb, hist, brec);
            else
                mscat_k<1024><<<dim3((unsigned)tc), 1024, 0, stream>>>(tb, hist, brec);
            long long gBase = eoffA[t0];
            mcsr_k<<<dim3((unsigned)tbn), 1024, 0, stream>>>(
                tb, brec, hist, starts, pool + gBase, (int)gBase);
            t0 = t1;
        }
    };

    // ---- feature buffers ----
    float* t   = ws + t_o;                   // [NF,16] fp pre-transform, 1-2
    float* c1  = ws + zC_o;                  // [N0,16], steps 2-18 (tail zone)
    float* tpc = c1;                         // steps 19.5-21 (c1 dead)
    size_t mb = zD_o;
    auto mal = [&](size_t n) { size_t o = mb; mb += pad4(n); return ws + o; };
    float* p1  = mal((size_t)N1c*16);
    float* c2  = mal((size_t)N1c*16);
    float* p2  = mal((size_t)N2c*16);
    float* c3  = mal((size_t)N2c*16);
    float* p3  = mal((size_t)N3c*16);
    float* c4  = mal((size_t)N3c*32);
    float* p4  = mal((size_t)N4c*32);
    float* c5a = mal((size_t)N4c*32);
    float* c5b = mal((size_t)N4c*32);
    float* t6  = mal((size_t)N3c*32);
    float* g6  = mal((size_t)N3c*32);
    float* t7  = mal((size_t)N2c*32);
    float* g7  = mal((size_t)N2c*32);
    float* t8  = mal((size_t)N1c*16);
    float* g8  = mal((size_t)N1c*16);        // arena ends ~zD_o+12.06M <= ZDCAP
    // t9 OVERLAYS zD_o[0,8M): at step 18 all mids below g8's 10.06M offset
    // are dead (p1..t8); g8 [10.06M,12.06M) and c1 (tail zone) are disjoint.
    float* t9  = ws + zD_o;
    float* out = (float*)d_out;

    // ---- Stage I: cf+fp CSRs (one group) + steps 1-2 ----
    int* startsI = (int*)(ws + 0);
    int2* poolI  = (int2*)(ws + pad4(sumNdPadI + 1));
    int doffI[2];
    buildStage(2, sI_in, sI_nd, startsI, poolI, doffI);
    // 1) fused: h = relu(gather(cf,xc)@W_cf+b_cf); t = [h||xf]@W_fp  [NF,16]
    cffp_k<<<G(NFc), B, 0, stream>>>(
        xc, xf, poolI, startsI + doffI[0], W_cf, b_cf, W_fp, t, NFc);
    // 2) c1 = relu(gather(fp, t) + b_fp)                       [N0,16]
    gather_sw_k<16,true><<<G(N0c), B, 0, stream>>>(
        t, poolI, startsI + doffI[1], b_fp, c1, N0c);

    // ---- Stage II: 14 remaining CSRs (2 groups; t dead) ----
    int* startsII = (int*)(ws + 0);
    int2* poolII  = (int2*)(ws + pad4(sumNdPadII + 1));
    int doffII[14];
    buildStage(14, sII_in, sII_nd, startsII, poolII, doffII);
    enum { f_pc, f_pp0, f_pp1, f_pp2, f_pp3, f_pp4, f_po0, f_po1, f_po2, f_po3,
           f_up0, f_up1, f_up2, f_up3 };
    auto st = [&](int t_) { return startsII + doffII[t_]; };
    int2* ec = poolII;

    // ---- Stage III: pipeline ----
    // 3) p1 = gather(pool0, c1)
    gather_sw_k<16,false><<<G(N1c), B, 0, stream>>>(c1, ec, st(f_po0), nullptr, p1, N1c);
    // 4) c2
    gather_conv_k<16,0,16><<<G(N1c), B, 0, stream>>>(p1, nullptr, ec, st(f_pp1), W2, b2, c2, N1c);
    // 5) p2
    gather_sw_k<16,false><<<G(N2c), B, 0, stream>>>(c2, ec, st(f_po1), nullptr, p2, N2c);
    // 6) c3
    gather_conv_k<16,0,16><<<G(N2c), B, 0, stream>>>(p2, nullptr, ec, st(f_pp2), W3, b3, c3, N2c);
    // 7) p3
    gather_sw_k<16,false><<<G(N3c), B, 0, stream>>>(c3, ec, st(f_po2), nullptr, p3, N3c);
    // 8) c4
    gather_conv_k<16,0,32><<<G(N3c), B, 0, stream>>>(p3, nullptr, ec, st(f_pp3), W4, b4, c4, N3c);
    // 9) p4
    gather_sw_k<32,false><<<G(N4c), B, 0, stream>>>(c4, ec, st(f_po3), nullptr, p4, N4c);
    // 10) c5a
    gather_conv_k<32,0,32><<<G(N4c), B, 0, stream>>>(p4, nullptr, ec, st(f_pp4), W5a, b5a, c5a, N4c);
    // 11) c5b
    gather_conv_k<32,0,32><<<G(N4c), B, 0, stream>>>(c5a, nullptr, ec, st(f_pp4), W5b, b5b, c5b, N4c);
    // 12+13a) t6 = [gather(unpool3, c5b) || c4] @ W6
    gather_dense_k<32,32,32,false><<<G(N3c), B, 0, stream>>>(
        c5b, c4, ec, st(f_up3), nullptr, W6, t6, N3c);
    // 13b) g6 = relu(gather(pp3, t6) + b6)
    gather_sw_k<32,true><<<G(N3c), B, 0, stream>>>(t6, ec, st(f_pp3), b6, g6, N3c);
    // 14+15a) t7 = [gather(unpool2, g6) || c3] @ W7
    gather_dense_k<32,16,32,false><<<G(N2c), B, 0, stream>>>(
        g6, c3, ec, st(f_up2), nullptr, W7, t7, N2c);
    // 15b) g7
    gather_sw_k<32,true><<<G(N2c), B, 0, stream>>>(t7, ec, st(f_pp2), b7, g7, N2c);
    // 16+17a) t8 = [gather(unpool1, g7) || c2] @ W8
    gather_dense_k<32,16,16,false><<<G(N1c), B, 0, stream>>>(
        g7, c2, ec, st(f_up1), nullptr, W8, t8, N1c);
    // 17b) g8
    gather_sw_k<16,true><<<G(N1c), B, 0, stream>>>(t8, ec, st(f_pp1), b8, g8, N1c);
    // 18+19a) t9 = [gather(unpool0, g8) || c1] @ W9a   (t9 overlays dead mids)
    gather_dense_k<16,16,16,false><<<G(N0c), B, 0, stream>>>(
        g8, c1, ec, st(f_up0), nullptr, W9a, t9, N0c);
    // 19b+20) tpc = relu(gather(pp0, t9) + b9a) @ W9b   (overlays c1)
    gather_dense_k<16,0,16,true><<<G(N0c), B, 0, stream>>>(
        t9, nullptr, ec, st(f_pp0), b9a, W9b, tpc, N0c);
    // 21) fused pc gather + bias + relu + Wf dot
    gather_final_k<<<G(NCc), B, 0, stream>>>(tpc, ec, st(f_pc), b9b, Wf, bfb, out, NCc);
}